// Round 2
// baseline (425.879 us; speedup 1.0000x reference)
//
#include <hip/hip_runtime.h>
#include <hip/hip_bf16.h>

// Problem constants (match reference)
#define N_NODES  100000
#define N_EDGES  1600000
#define N_GRAPHS 2048
#define DIM      128   // IN_DIM == HIDDEN == 128
#define ELLW     64    // padded edges/node; deg ~ Poisson(16), max ~40

// ---- bf16 helpers (RNE encode, bit-shift decode) --------------------------
__device__ __forceinline__ unsigned short f2b(float f) {
    unsigned u = __float_as_uint(f);
    u += 0x7FFFu + ((u >> 16) & 1u);
    return (unsigned short)(u >> 16);
}
__device__ __forceinline__ float b2f(unsigned short h) {
    return __uint_as_float(((unsigned)h) << 16);
}
__device__ __forceinline__ float4 dec4(ushort4 h) {
    return make_float4(b2f(h.x), b2f(h.y), b2f(h.z), b2f(h.w));
}

// MFMA fragment types (gfx950, 16x16x32 bf16: 8 bf16 in / 4 fp32 acc)
typedef __attribute__((ext_vector_type(8))) short bfrag;
typedef __attribute__((ext_vector_type(4))) float ffrag;

// ===========================================================================
// Cast fp32 -> bf16 (8 elems/thread). Also: zeroes cursor[] and casts+
// transposes the 3 weights (first 49152 threads) -- one dispatch fewer.
// ===========================================================================
__global__ __launch_bounds__(256)
void cast_bf16(const float* __restrict__ in, unsigned short* __restrict__ out,
               int* __restrict__ cursor,
               const float* __restrict__ Wa, unsigned short* __restrict__ Ta,
               const float* __restrict__ Wb, unsigned short* __restrict__ Tb,
               const float* __restrict__ Wc, unsigned short* __restrict__ Tc,
               int n8)
{
    int i = blockIdx.x * 256 + threadIdx.x;
    if (i < N_NODES) cursor[i] = 0;
    if (i < 3 * DIM * DIM) {
        int which = i >> 14;              // 16384 elems per weight
        int idx   = i & (DIM * DIM - 1);
        const float* W = (which == 0) ? Wa : (which == 1) ? Wb : Wc;
        unsigned short* T = (which == 0) ? Ta : (which == 1) ? Tb : Tc;
        int k = idx >> 7, n = idx & 127;
        T[n * DIM + k] = f2b(W[idx]);
    }
    if (i >= n8) return;
    const float4* in4 = (const float4*)in;
    float4 a = in4[i * 2 + 0];
    float4 b = in4[i * 2 + 1];
    uint4 q;
    q.x = (unsigned)f2b(a.x) | ((unsigned)f2b(a.y) << 16);
    q.y = (unsigned)f2b(a.z) | ((unsigned)f2b(a.w) << 16);
    q.z = (unsigned)f2b(b.x) | ((unsigned)f2b(b.y) << 16);
    q.w = (unsigned)f2b(b.z) | ((unsigned)f2b(b.w) << 16);
    ((uint4*)out)[i] = q;
}

// ===========================================================================
// ELL fill: pos = cursor[dst]++;  ell[dst*ELLW + pos] = src
// XCD-range-partitioned (round-4 win): range r = blockIdx&7 owns dst in
// [r*12500,(r+1)*12500) -> per-range ELL window 3.2 MB < 4 MB L2.
// Also zeroes g[] (1024 blocks x 256 = exactly N_GRAPHS*DIM).
// ===========================================================================
#define FILL_RANGES 8
#define FILL_RSIZE  (N_NODES / FILL_RANGES)   // 12500 exact

__global__ __launch_bounds__(256)
void ell_fill(const int* __restrict__ src, const int* __restrict__ dst,
              int* __restrict__ cursor, int* __restrict__ ell,
              float* __restrict__ g, int E)
{
    int gid = blockIdx.x * 256 + threadIdx.x;   // grid=1024 -> covers |g|
    g[gid] = 0.f;

    const int r = blockIdx.x & (FILL_RANGES - 1);
    const int s = blockIdx.x >> 3;
    const int nslice = gridDim.x >> 3;
    const unsigned lo = (unsigned)(r * FILL_RSIZE);
    const int stride = nslice * 256 * 4;

    for (int e0 = (s * 256 + threadIdx.x) * 4; e0 < E; e0 += stride) {
        int4 d  = *(const int4*)&dst[e0];
        int4 sv = *(const int4*)&src[e0];
        if ((unsigned)(d.x - lo) < (unsigned)FILL_RSIZE) {
            int p = atomicAdd(&cursor[d.x], 1); ell[d.x * ELLW + p] = sv.x;
        }
        if ((unsigned)(d.y - lo) < (unsigned)FILL_RSIZE) {
            int p = atomicAdd(&cursor[d.y], 1); ell[d.y * ELLW + p] = sv.y;
        }
        if ((unsigned)(d.z - lo) < (unsigned)FILL_RSIZE) {
            int p = atomicAdd(&cursor[d.z], 1); ell[d.z * ELLW + p] = sv.z;
        }
        if ((unsigned)(d.w - lo) < (unsigned)FILL_RSIZE) {
            int p = atomicAdd(&cursor[d.w], 1); ell[d.w * ELLW + p] = sv.w;
        }
    }
}

// ===========================================================================
// FUSED: GIN ELL-gather (bf16, fp32 acc) directly into the MLP's LDS H tile,
// then the 3-layer MLP via MFMA 16x16x32 bf16.
// Round-1 regression root-cause: Ws LDS staging (34.8K) capped residency at
// 3 blocks/CU (occupancy 25%) and starved the random-gather of outstanding
// loads (hbm 2.7->1.67 TB/s). Fix: read B-fragments DIRECTLY from global.
// The 3x32 KB weights are read by every block -> L1-resident (32 KB/CU) and
// L2-hot; LDS drops to 17.7 KB -> 8 blocks/CU (100% wave cap).
// Bonus: all LDS rows are wave-private (wave w = gather grps 2w,2w+1 = rows
// 16w..16w+15 = its MFMA A/C rows), so NO per-layer barriers -- waves run
// independently; MFMA of early waves overlaps gather tails of late ones.
// A-frag: A[m=lane&15][k=quad*8+j]; B-frag from Wt[n][k] (row-major, n fast);
// C/D: col=lane&15, row=quad*4+reg (verified layouts, m89/m120).
// ===========================================================================
#define MLP_ROWS 64
#define HBST     136

__global__ __launch_bounds__(256)
void mlp3_fused(const int* __restrict__ deg, const int* __restrict__ ell,
                const unsigned short* __restrict__ xb,
                const unsigned short* __restrict__ w1t, const float* __restrict__ b1,
                const unsigned short* __restrict__ w2t, const float* __restrict__ b2,
                const unsigned short* __restrict__ w3t,
                unsigned short* __restrict__ ub_out, int N)
{
    __shared__ unsigned short Hb[MLP_ROWS][HBST];
    __shared__ float dvs[MLP_ROWS];

    const int tid  = threadIdx.x;
    const int row0 = blockIdx.x * MLP_ROWS;

    // ---- gather phase: H[r] = x[node] + sum_{e<deg} x[ell[node][e]] -------
    {
        const int grp = tid >> 5;        // 0..7: rows grp*8..grp*8+7
        const int gl  = tid & 31;        // lane covers cols gl*4..gl*4+3
        const ushort4* V4 = (const ushort4*)xb;
        for (int k = 0; k < 8; ++k) {
            int r = grp * 8 + k;
            int node = row0 + r;
            if (node >= N) break;
            int dn = deg[node];
            if (gl == 0) dvs[r] = rsqrtf((float)dn + 1.0f);
            const int* row = ell + (size_t)node * ELLW;
            float4 acc = dec4(V4[(size_t)node * 32 + gl]);   // self term
            int e = 0;
            for (; e + 8 <= dn; e += 8) {
                int s0 = row[e + 0], s1 = row[e + 1], s2 = row[e + 2], s3 = row[e + 3];
                int s4 = row[e + 4], s5 = row[e + 5], s6 = row[e + 6], s7 = row[e + 7];
                float4 v0 = dec4(V4[(size_t)s0 * 32 + gl]);
                float4 v1 = dec4(V4[(size_t)s1 * 32 + gl]);
                float4 v2 = dec4(V4[(size_t)s2 * 32 + gl]);
                float4 v3 = dec4(V4[(size_t)s3 * 32 + gl]);
                float4 v4 = dec4(V4[(size_t)s4 * 32 + gl]);
                float4 v5 = dec4(V4[(size_t)s5 * 32 + gl]);
                float4 v6 = dec4(V4[(size_t)s6 * 32 + gl]);
                float4 v7 = dec4(V4[(size_t)s7 * 32 + gl]);
                acc.x += (v0.x + v1.x + v2.x + v3.x) + (v4.x + v5.x + v6.x + v7.x);
                acc.y += (v0.y + v1.y + v2.y + v3.y) + (v4.y + v5.y + v6.y + v7.y);
                acc.z += (v0.z + v1.z + v2.z + v3.z) + (v4.z + v5.z + v6.z + v7.z);
                acc.w += (v0.w + v1.w + v2.w + v3.w) + (v4.w + v5.w + v6.w + v7.w);
            }
            for (; e + 4 <= dn; e += 4) {
                int s0 = row[e + 0], s1 = row[e + 1], s2 = row[e + 2], s3 = row[e + 3];
                float4 v0 = dec4(V4[(size_t)s0 * 32 + gl]);
                float4 v1 = dec4(V4[(size_t)s1 * 32 + gl]);
                float4 v2 = dec4(V4[(size_t)s2 * 32 + gl]);
                float4 v3 = dec4(V4[(size_t)s3 * 32 + gl]);
                acc.x += v0.x + v1.x + v2.x + v3.x;
                acc.y += v0.y + v1.y + v2.y + v3.y;
                acc.z += v0.z + v1.z + v2.z + v3.z;
                acc.w += v0.w + v1.w + v2.w + v3.w;
            }
            for (; e < dn; ++e) {
                int s = row[e];
                float4 v = dec4(V4[(size_t)s * 32 + gl]);
                acc.x += v.x; acc.y += v.y; acc.z += v.z; acc.w += v.w;
            }
            ushort4 o;
            o.x = f2b(acc.x); o.y = f2b(acc.y); o.z = f2b(acc.z); o.w = f2b(acc.w);
            *(ushort4*)&Hb[r][gl * 4] = o;
        }
    }
    // rows/dvs are wave-private; single barrier kept as a safety fence only
    __syncthreads();

    const int wave = tid >> 6;        // 0..3
    const int lane = tid & 63;
    const int m0 = wave * 16;
    const int qa = lane >> 4;         // quad 0..3
    const int la = lane & 15;

    for (int layer = 0; layer < 3; ++layer) {
        const unsigned short* __restrict__ Wt =
            (layer == 0) ? w1t : (layer == 1) ? w2t : w3t;

        // A fragments for this wave's 16 rows, all K (4 chunks of 32)
        bfrag afr[4];
#pragma unroll
        for (int kc = 0; kc < 4; ++kc)
            afr[kc] = *(const bfrag*)&Hb[m0 + la][kc * 32 + qa * 8];

        if (layer < 2) {
            const float* bias = (layer == 0) ? b1 : b2;
#pragma unroll
            for (int nt = 0; nt < 8; ++nt) {
                const int n0 = nt * 16;
                const unsigned short* wrow = Wt + (size_t)(n0 + la) * DIM + qa * 8;
                ffrag acc = {0.f, 0.f, 0.f, 0.f};
#pragma unroll
                for (int kc = 0; kc < 4; ++kc) {
                    bfrag bfr = *(const bfrag*)(wrow + kc * 32);
                    acc = __builtin_amdgcn_mfma_f32_16x16x32_bf16(afr[kc], bfr, acc, 0, 0, 0);
                }
                float bn = bias[n0 + la];
#pragma unroll
                for (int r = 0; r < 4; ++r) {
                    float v = fmaxf(acc[r] + bn, 0.f);
                    Hb[m0 + qa * 4 + r][n0 + la] = f2b(v);
                }
            }
            // wave-private rows: program order suffices before next layer
        } else {
            float dv[4];
#pragma unroll
            for (int r = 0; r < 4; ++r)
                dv[r] = dvs[m0 + qa * 4 + r];   // garbage for rows >= N: store guarded
#pragma unroll
            for (int nt = 0; nt < 8; ++nt) {
                const int n0 = nt * 16;
                const unsigned short* wrow = Wt + (size_t)(n0 + la) * DIM + qa * 8;
                ffrag acc = {0.f, 0.f, 0.f, 0.f};
#pragma unroll
                for (int kc = 0; kc < 4; ++kc) {
                    bfrag bfr = *(const bfrag*)(wrow + kc * 32);
                    acc = __builtin_amdgcn_mfma_f32_16x16x32_bf16(afr[kc], bfr, acc, 0, 0, 0);
                }
#pragma unroll
                for (int r = 0; r < 4; ++r) {
                    int gr = row0 + m0 + qa * 4 + r;
                    if (gr < N)
                        ub_out[(size_t)gr * DIM + n0 + la] = f2b(dv[r] * acc[r]);
                }
            }
        }
    }
}

// ===========================================================================
// Fused GCN gather (bf16 u, ELL) + finalize + global_add_pool.
// P2_NODES=64 (8 sequential nodes per 32-lane group): round-13 showed 32
// doubles pool-atomic WRITE (28.6->53 MB) and regresses 82->97 us; run-length
// batching needs the longer per-group node run. Occupancy is NOT the pool's
// limiter at 51% (random-read delivery plateau is) -- but IS below ~40%
// (round-1 lesson).
// dinv computed locally from deg (same rsqrtf as producer -> bit-identical).
// ===========================================================================
#define P2_NODES 64
__global__ __launch_bounds__(256)
void gcn_gather_pool(const int* __restrict__ deg, const int* __restrict__ ell,
                     const unsigned short* __restrict__ ub,
                     const float* __restrict__ bias, const int* __restrict__ batch,
                     float* __restrict__ g, int N)
{
    const int grp  = threadIdx.x >> 5;
    const int lane = threadIdx.x & 31;
    const int n0   = blockIdx.x * P2_NODES + grp * 8;
    const ushort4* V4 = (const ushort4*)ub;

    float4 bj;
    bj.x = bias[lane * 4 + 0];
    bj.y = bias[lane * 4 + 1];
    bj.z = bias[lane * 4 + 2];
    bj.w = bias[lane * 4 + 3];

    float4 lsum = make_float4(0.f, 0.f, 0.f, 0.f);
    int prev = -1;

    for (int k = 0; k < 8; ++k) {
        int node = n0 + k;
        if (node >= N) break;
        int dn = deg[node];
        const int* row = ell + node * ELLW;
        float4 acc = dec4(V4[(size_t)node * 32 + lane]);   // self term u_i
        int e = 0;
        for (; e + 8 <= dn; e += 8) {
            int s0 = row[e + 0], s1 = row[e + 1], s2 = row[e + 2], s3 = row[e + 3];
            int s4 = row[e + 4], s5 = row[e + 5], s6 = row[e + 6], s7 = row[e + 7];
            float4 v0 = dec4(V4[(size_t)s0 * 32 + lane]);
            float4 v1 = dec4(V4[(size_t)s1 * 32 + lane]);
            float4 v2 = dec4(V4[(size_t)s2 * 32 + lane]);
            float4 v3 = dec4(V4[(size_t)s3 * 32 + lane]);
            float4 v4 = dec4(V4[(size_t)s4 * 32 + lane]);
            float4 v5 = dec4(V4[(size_t)s5 * 32 + lane]);
            float4 v6 = dec4(V4[(size_t)s6 * 32 + lane]);
            float4 v7 = dec4(V4[(size_t)s7 * 32 + lane]);
            acc.x += (v0.x + v1.x + v2.x + v3.x) + (v4.x + v5.x + v6.x + v7.x);
            acc.y += (v0.y + v1.y + v2.y + v3.y) + (v4.y + v5.y + v6.y + v7.y);
            acc.z += (v0.z + v1.z + v2.z + v3.z) + (v4.z + v5.z + v6.z + v7.z);
            acc.w += (v0.w + v1.w + v2.w + v3.w) + (v4.w + v5.w + v6.w + v7.w);
        }
        for (; e + 4 <= dn; e += 4) {
            int s0 = row[e + 0], s1 = row[e + 1], s2 = row[e + 2], s3 = row[e + 3];
            float4 v0 = dec4(V4[(size_t)s0 * 32 + lane]);
            float4 v1 = dec4(V4[(size_t)s1 * 32 + lane]);
            float4 v2 = dec4(V4[(size_t)s2 * 32 + lane]);
            float4 v3 = dec4(V4[(size_t)s3 * 32 + lane]);
            acc.x += v0.x + v1.x + v2.x + v3.x;
            acc.y += v0.y + v1.y + v2.y + v3.y;
            acc.z += v0.z + v1.z + v2.z + v3.z;
            acc.w += v0.w + v1.w + v2.w + v3.w;
        }
        for (; e < dn; ++e) {
            int s = row[e];
            float4 v = dec4(V4[(size_t)s * 32 + lane]);
            acc.x += v.x; acc.y += v.y; acc.z += v.z; acc.w += v.w;
        }
        float di = rsqrtf((float)dn + 1.0f);
        float4 h;
        h.x = fmaxf(fmaf(di, acc.x, bj.x), 0.f);
        h.y = fmaxf(fmaf(di, acc.y, bj.y), 0.f);
        h.z = fmaxf(fmaf(di, acc.z, bj.z), 0.f);
        h.w = fmaxf(fmaf(di, acc.w, bj.w), 0.f);

        int b = batch[node];
        if (b != prev) {
            if (prev >= 0) {
                float* gp = &g[(size_t)prev * DIM + lane * 4];
                atomicAdd(gp + 0, lsum.x);
                atomicAdd(gp + 1, lsum.y);
                atomicAdd(gp + 2, lsum.z);
                atomicAdd(gp + 3, lsum.w);
            }
            lsum = make_float4(0.f, 0.f, 0.f, 0.f);
            prev = b;
        }
        lsum.x += h.x; lsum.y += h.y; lsum.z += h.z; lsum.w += h.w;
    }
    if (prev >= 0) {
        float* gp = &g[(size_t)prev * DIM + lane * 4];
        atomicAdd(gp + 0, lsum.x);
        atomicAdd(gp + 1, lsum.y);
        atomicAdd(gp + 2, lsum.z);
        atomicAdd(gp + 3, lsum.w);
    }
}

// ===========================================================================
// Head: out[gid] = relu(g[gid] @ lin1_w + b1) @ lin2_w + b2
// ===========================================================================
__global__ __launch_bounds__(128)
void head_kernel(const float* __restrict__ g, const float* __restrict__ w1,
                 const float* __restrict__ b1, const float* __restrict__ w2,
                 const float* __restrict__ b2, float* __restrict__ out)
{
    __shared__ float gs[DIM];
    __shared__ float red[6];
    int gid = blockIdx.x;
    int t = threadIdx.x;

    gs[t] = g[(size_t)gid * DIM + t];
    __syncthreads();

    float acc = b1[t];
#pragma unroll
    for (int k = 0; k < DIM; ++k) acc = fmaf(gs[k], w1[k * DIM + t], acc);
    float h = fmaxf(acc, 0.f);

    float c0 = h * w2[t * 3 + 0];
    float c1 = h * w2[t * 3 + 1];
    float c2 = h * w2[t * 3 + 2];
#pragma unroll
    for (int off = 32; off >= 1; off >>= 1) {
        c0 += __shfl_down(c0, off);
        c1 += __shfl_down(c1, off);
        c2 += __shfl_down(c2, off);
    }
    int wave = t >> 6;
    if ((t & 63) == 0) {
        red[wave * 3 + 0] = c0;
        red[wave * 3 + 1] = c1;
        red[wave * 3 + 2] = c2;
    }
    __syncthreads();
    if (t == 0) {
        out[(size_t)gid * 3 + 0] = red[0] + red[3] + b2[0];
        out[(size_t)gid * 3 + 1] = red[1] + red[4] + b2[1];
        out[(size_t)gid * 3 + 2] = red[2] + red[5] + b2[2];
    }
}

// ===========================================================================
extern "C" void kernel_launch(void* const* d_in, const int* in_sizes, int n_in,
                              void* d_out, int out_size, void* d_ws, size_t ws_size,
                              hipStream_t stream)
{
    const float* x       = (const float*)d_in[0];
    const int*   eidx    = (const int*)d_in[1];
    const int*   batch   = (const int*)d_in[2];
    const float* gin_w1  = (const float*)d_in[3];
    const float* gin_b1  = (const float*)d_in[4];
    const float* gin_w2  = (const float*)d_in[5];
    const float* gin_b2  = (const float*)d_in[6];
    const float* gcn_w   = (const float*)d_in[7];
    const float* gcn_b   = (const float*)d_in[8];
    const float* lin1_w  = (const float*)d_in[9];
    const float* lin1_b  = (const float*)d_in[10];
    const float* lin2_w  = (const float*)d_in[11];
    const float* lin2_b  = (const float*)d_in[12];

    const int* src = eidx;
    const int* dst = eidx + N_EDGES;

    // workspace carve (256B aligned); total ~78 MB
    const size_t NBH = (size_t)N_NODES * DIM * sizeof(unsigned short); // 25.6 MB
    const size_t WTB = (size_t)DIM * DIM * sizeof(unsigned short);     // 32 KB
    char* base = (char*)d_ws;
    size_t off = 0;
    auto carve = [&](size_t bytes) {
        char* p = base + off;
        off = (off + bytes + 255) & ~(size_t)255;
        return p;
    };
    unsigned short* xb  = (unsigned short*)carve(NBH);  // x in bf16
    unsigned short* ub  = (unsigned short*)carve(NBH);  // u in bf16
    unsigned short* w1t = (unsigned short*)carve(WTB);  // gin_w1^T bf16
    unsigned short* w2t = (unsigned short*)carve(WTB);
    unsigned short* w3t = (unsigned short*)carve(WTB);
    int*   cursor = (int*)  carve(N_NODES * sizeof(int));              // -> deg
    int*   ell    = (int*)  carve((size_t)N_NODES * ELLW * sizeof(int)); // 25.6MB
    float* g      = (float*)carve((size_t)N_GRAPHS * DIM * sizeof(float));

    const int mgrid = (N_NODES + MLP_ROWS - 1) / MLP_ROWS;
    const int pgrid = (N_NODES + P2_NODES - 1) / P2_NODES;

    // ---- casts + weight transpose + cursor zeroing (one dispatch) ----
    cast_bf16<<<(N_NODES * DIM / 8 + 255) / 256, 256, 0, stream>>>(
        x, xb, cursor, gin_w1, w1t, gin_w2, w2t, gcn_w, w3t,
        N_NODES * DIM / 8);

    // ---- ELL build (also zeroes g); cursor ends as degree ----
    ell_fill<<<FILL_RANGES * 128, 256, 0, stream>>>(src, dst, cursor, ell,
                                                    g, N_EDGES);

    // ---- fused GIN gather + 3-layer MLP via MFMA (B from L1/L2) -> u ----
    mlp3_fused<<<mgrid, 256, 0, stream>>>(cursor, ell, xb, w1t, gin_b1,
                                          w2t, gin_b2, w3t, ub, N_NODES);

    // ---- fused GCN gather (bf16) + finalize + pool -> g ----
    gcn_gather_pool<<<pgrid, 256, 0, stream>>>(cursor, ell, ub, gcn_b,
                                               batch, g, N_NODES);

    // ---- head ----
    head_kernel<<<N_GRAPHS, 128, 0, stream>>>(
        g, lin1_w, lin1_b, lin2_w, lin2_b, (float*)d_out);
}

// Round 3
// 363.413 us; speedup vs baseline: 1.1719x; 1.1719x over previous
//
#include <hip/hip_runtime.h>
#include <hip/hip_bf16.h>

// Problem constants (match reference)
#define N_NODES  100000
#define N_EDGES  1600000
#define N_GRAPHS 2048
#define DIM      128   // IN_DIM == HIDDEN == 128
#define ELLW     64    // padded edges/node; deg ~ Poisson(16), max ~40

// ---- bf16 helpers (RNE encode, bit-shift decode) --------------------------
__device__ __forceinline__ unsigned short f2b(float f) {
    unsigned u = __float_as_uint(f);
    u += 0x7FFFu + ((u >> 16) & 1u);
    return (unsigned short)(u >> 16);
}
__device__ __forceinline__ float b2f(unsigned short h) {
    return __uint_as_float(((unsigned)h) << 16);
}
__device__ __forceinline__ float4 dec4(ushort4 h) {
    return make_float4(b2f(h.x), b2f(h.y), b2f(h.z), b2f(h.w));
}

// MFMA fragment types (gfx950, 16x16x32 bf16: 8 bf16 in / 4 fp32 acc)
typedef __attribute__((ext_vector_type(8))) short bfrag;
typedef __attribute__((ext_vector_type(4))) float ffrag;

// ===========================================================================
// Cast fp32 -> bf16 (8 elems/thread). Also: zeroes cursor[] and casts+
// transposes the 3 weights (first 49152 threads) -- one dispatch fewer.
// ===========================================================================
__global__ __launch_bounds__(256)
void cast_bf16(const float* __restrict__ in, unsigned short* __restrict__ out,
               int* __restrict__ cursor,
               const float* __restrict__ Wa, unsigned short* __restrict__ Ta,
               const float* __restrict__ Wb, unsigned short* __restrict__ Tb,
               const float* __restrict__ Wc, unsigned short* __restrict__ Tc,
               int n8)
{
    int i = blockIdx.x * 256 + threadIdx.x;
    if (i < N_NODES) cursor[i] = 0;
    if (i < 3 * DIM * DIM) {
        int which = i >> 14;              // 16384 elems per weight
        int idx   = i & (DIM * DIM - 1);
        const float* W = (which == 0) ? Wa : (which == 1) ? Wb : Wc;
        unsigned short* T = (which == 0) ? Ta : (which == 1) ? Tb : Tc;
        int k = idx >> 7, n = idx & 127;
        T[n * DIM + k] = f2b(W[idx]);
    }
    if (i >= n8) return;
    const float4* in4 = (const float4*)in;
    float4 a = in4[i * 2 + 0];
    float4 b = in4[i * 2 + 1];
    uint4 q;
    q.x = (unsigned)f2b(a.x) | ((unsigned)f2b(a.y) << 16);
    q.y = (unsigned)f2b(a.z) | ((unsigned)f2b(a.w) << 16);
    q.z = (unsigned)f2b(b.x) | ((unsigned)f2b(b.y) << 16);
    q.w = (unsigned)f2b(b.z) | ((unsigned)f2b(b.w) << 16);
    ((uint4*)out)[i] = q;
}

// ===========================================================================
// ELL fill: pos = cursor[dst]++;  ell[dst*ELLW + pos] = src
// XCD-range-partitioned (round-4 win): range r = blockIdx&7 owns dst in
// [r*12500,(r+1)*12500) -> per-range ELL window 3.2 MB < 4 MB L2.
// Also zeroes g[] (1024 blocks x 256 = exactly N_GRAPHS*DIM).
// ===========================================================================
#define FILL_RANGES 8
#define FILL_RSIZE  (N_NODES / FILL_RANGES)   // 12500 exact

__global__ __launch_bounds__(256)
void ell_fill(const int* __restrict__ src, const int* __restrict__ dst,
              int* __restrict__ cursor, int* __restrict__ ell,
              float* __restrict__ g, int E)
{
    int gid = blockIdx.x * 256 + threadIdx.x;   // grid=1024 -> covers |g|
    g[gid] = 0.f;

    const int r = blockIdx.x & (FILL_RANGES - 1);
    const int s = blockIdx.x >> 3;
    const int nslice = gridDim.x >> 3;
    const unsigned lo = (unsigned)(r * FILL_RSIZE);
    const int stride = nslice * 256 * 4;

    for (int e0 = (s * 256 + threadIdx.x) * 4; e0 < E; e0 += stride) {
        int4 d  = *(const int4*)&dst[e0];
        int4 sv = *(const int4*)&src[e0];
        if ((unsigned)(d.x - lo) < (unsigned)FILL_RSIZE) {
            int p = atomicAdd(&cursor[d.x], 1); ell[d.x * ELLW + p] = sv.x;
        }
        if ((unsigned)(d.y - lo) < (unsigned)FILL_RSIZE) {
            int p = atomicAdd(&cursor[d.y], 1); ell[d.y * ELLW + p] = sv.y;
        }
        if ((unsigned)(d.z - lo) < (unsigned)FILL_RSIZE) {
            int p = atomicAdd(&cursor[d.z], 1); ell[d.z * ELLW + p] = sv.z;
        }
        if ((unsigned)(d.w - lo) < (unsigned)FILL_RSIZE) {
            int p = atomicAdd(&cursor[d.w], 1); ell[d.w * ELLW + p] = sv.w;
        }
    }
}

// ===========================================================================
// bf16 ELL gather -> bf16 out: Out[i] = Vb[i] + sum_{e<deg[i]} Vb[ell[i][e]]
// (fp32 accumulate). Lane 0 also writes dinv[i] = rsqrt(deg+1).
// One node per 32-lane group, ushort4 per lane, x8/x4/x1 unroll tiers.
// 12500-block oversubscription is REQUIRED for the random-read delivery
// plateau (round-1/2 lesson: fused 1563-block variants dropped to 1.3-1.7
// TB/s and regressed +29/+59 us).
// ===========================================================================
__global__ __launch_bounds__(256)
void ell_gather_bb(const int* __restrict__ deg, const int* __restrict__ ell,
                   const unsigned short* __restrict__ Vb,
                   unsigned short* __restrict__ Out,
                   float* __restrict__ dinv, int N)
{
    int node = blockIdx.x * 8 + (threadIdx.x >> 5);
    int lane = threadIdx.x & 31;
    if (node >= N) return;
    int dn = deg[node];
    if (lane == 0) dinv[node] = rsqrtf((float)dn + 1.0f);
    const int* row = ell + node * ELLW;
    const ushort4* V4 = (const ushort4*)Vb;
    float4 acc = dec4(V4[(size_t)node * 32 + lane]);   // self term
    int e = 0;
    for (; e + 8 <= dn; e += 8) {
        int s0 = row[e + 0], s1 = row[e + 1], s2 = row[e + 2], s3 = row[e + 3];
        int s4 = row[e + 4], s5 = row[e + 5], s6 = row[e + 6], s7 = row[e + 7];
        float4 v0 = dec4(V4[(size_t)s0 * 32 + lane]);
        float4 v1 = dec4(V4[(size_t)s1 * 32 + lane]);
        float4 v2 = dec4(V4[(size_t)s2 * 32 + lane]);
        float4 v3 = dec4(V4[(size_t)s3 * 32 + lane]);
        float4 v4 = dec4(V4[(size_t)s4 * 32 + lane]);
        float4 v5 = dec4(V4[(size_t)s5 * 32 + lane]);
        float4 v6 = dec4(V4[(size_t)s6 * 32 + lane]);
        float4 v7 = dec4(V4[(size_t)s7 * 32 + lane]);
        acc.x += (v0.x + v1.x + v2.x + v3.x) + (v4.x + v5.x + v6.x + v7.x);
        acc.y += (v0.y + v1.y + v2.y + v3.y) + (v4.y + v5.y + v6.y + v7.y);
        acc.z += (v0.z + v1.z + v2.z + v3.z) + (v4.z + v5.z + v6.z + v7.z);
        acc.w += (v0.w + v1.w + v2.w + v3.w) + (v4.w + v5.w + v6.w + v7.w);
    }
    for (; e + 4 <= dn; e += 4) {
        int s0 = row[e + 0], s1 = row[e + 1], s2 = row[e + 2], s3 = row[e + 3];
        float4 v0 = dec4(V4[(size_t)s0 * 32 + lane]);
        float4 v1 = dec4(V4[(size_t)s1 * 32 + lane]);
        float4 v2 = dec4(V4[(size_t)s2 * 32 + lane]);
        float4 v3 = dec4(V4[(size_t)s3 * 32 + lane]);
        acc.x += v0.x + v1.x + v2.x + v3.x;
        acc.y += v0.y + v1.y + v2.y + v3.y;
        acc.z += v0.z + v1.z + v2.z + v3.z;
        acc.w += v0.w + v1.w + v2.w + v3.w;
    }
    for (; e < dn; ++e) {
        int s = row[e];
        float4 v = dec4(V4[(size_t)s * 32 + lane]);
        acc.x += v.x; acc.y += v.y; acc.z += v.z; acc.w += v.w;
    }
    ushort4 o;
    o.x = f2b(acc.x); o.y = f2b(acc.y); o.z = f2b(acc.z); o.w = f2b(acc.w);
    ((ushort4*)Out)[(size_t)node * 32 + lane] = o;
}

// ===========================================================================
// Fused 3-layer MLP via MFMA 16x16x32 bf16 (fp32 accumulate), W staged in LDS
// (round-10 win; round-2 lesson: global-B MFMA is latency-bound, keep LDS).
// Block = 256 thr = 4 waves; 64 rows; wave w owns 16 rows (row-parallel).
// LDS: Hb 17.4K + Ws 34.8K = 52.2K -> 3 blocks/CU.
// A-frag: A[m=lane&15][k=quad*8+j]; B-frag from Ws[n][k];
// C/D: col=lane&15, row=quad*4+reg (verified layouts, m89/m120).
// ===========================================================================
#define MLP_ROWS 64
#define HBST     136

__global__ __launch_bounds__(256)
void mlp3_mfma(const unsigned short* __restrict__ Hg,
               const unsigned short* __restrict__ w1t, const float* __restrict__ b1,
               const unsigned short* __restrict__ w2t, const float* __restrict__ b2,
               const unsigned short* __restrict__ w3t, const float* __restrict__ dinv,
               unsigned short* __restrict__ ub_out, int N)
{
    __shared__ unsigned short Hb[MLP_ROWS][HBST];
    __shared__ unsigned short Ws[DIM][HBST];

    const int tid  = threadIdx.x;
    const int wave = tid >> 6;        // 0..3
    const int lane = tid & 63;
    const int row0 = blockIdx.x * MLP_ROWS;

    // ---- load H tile (coalesced uint4 = 8 bf16): 1024 x 16 B, 4/thread ----
#pragma unroll
    for (int l = 0; l < 4; ++l) {
        int f  = tid + l * 256;       // 0..1023
        int r  = f >> 4;              // 0..63
        int c8 = (f & 15) << 3;       // 0,8,...,120
        int gr = row0 + r;
        uint4 v = make_uint4(0u, 0u, 0u, 0u);
        if (gr < N) v = *(const uint4*)&Hg[(size_t)gr * DIM + c8];
        *(uint4*)&Hb[r][c8] = v;
    }

    const int m0 = wave * 16;
    const int qa = lane >> 4;         // quad 0..3
    const int la = lane & 15;

    for (int layer = 0; layer < 3; ++layer) {
        const unsigned short* __restrict__ Wt =
            (layer == 0) ? w1t : (layer == 1) ? w2t : w3t;

        // ---- stage Wt[128][128] -> Ws: 2048 uint4, 8/thread (L2-hot) ----
        __syncthreads();   // prior-layer Ws reads (and layer-0 H load) done
#pragma unroll
        for (int l = 0; l < 8; ++l) {
            int f  = tid + l * 256;   // 0..2047
            int r  = f >> 4;          // 0..127
            int c8 = (f & 15) << 3;
            *(uint4*)&Ws[r][c8] = *(const uint4*)&Wt[(size_t)r * DIM + c8];
        }
        __syncthreads();

        // A fragments for this wave's 16 rows, all K (4 chunks of 32)
        bfrag afr[4];
#pragma unroll
        for (int kc = 0; kc < 4; ++kc)
            afr[kc] = *(const bfrag*)&Hb[m0 + la][kc * 32 + qa * 8];

        if (layer < 2) {
            const float* bias = (layer == 0) ? b1 : b2;
#pragma unroll
            for (int nt = 0; nt < 8; ++nt) {
                const int n0 = nt * 16;
                ffrag acc = {0.f, 0.f, 0.f, 0.f};
#pragma unroll
                for (int kc = 0; kc < 4; ++kc) {
                    bfrag bfr = *(const bfrag*)&Ws[n0 + la][kc * 32 + qa * 8];
                    acc = __builtin_amdgcn_mfma_f32_16x16x32_bf16(afr[kc], bfr, acc, 0, 0, 0);
                }
                float bn = bias[n0 + la];
#pragma unroll
                for (int r = 0; r < 4; ++r) {
                    float v = fmaxf(acc[r] + bn, 0.f);
                    Hb[m0 + qa * 4 + r][n0 + la] = f2b(v);
                }
            }
            // wave-private rows: program order suffices before next layer
        } else {
            float dv[4];
#pragma unroll
            for (int r = 0; r < 4; ++r) {
                int gr = row0 + m0 + qa * 4 + r;
                dv[r] = (gr < N) ? dinv[gr] : 0.f;
            }
#pragma unroll
            for (int nt = 0; nt < 8; ++nt) {
                const int n0 = nt * 16;
                ffrag acc = {0.f, 0.f, 0.f, 0.f};
#pragma unroll
                for (int kc = 0; kc < 4; ++kc) {
                    bfrag bfr = *(const bfrag*)&Ws[n0 + la][kc * 32 + qa * 8];
                    acc = __builtin_amdgcn_mfma_f32_16x16x32_bf16(afr[kc], bfr, acc, 0, 0, 0);
                }
#pragma unroll
                for (int r = 0; r < 4; ++r) {
                    int gr = row0 + m0 + qa * 4 + r;
                    if (gr < N)
                        ub_out[(size_t)gr * DIM + n0 + la] = f2b(dv[r] * acc[r]);
                }
            }
        }
    }
}

// ===========================================================================
// Fused GCN gather (bf16 u, ELL) + finalize + global_add_pool.
// P2_NODES=64 (8 sequential nodes per 32-lane group): round-13 showed 32
// doubles pool-atomic WRITE (28.6->53 MB) and regresses 82->97 us; run-length
// batching needs the longer per-group node run. Occupancy is NOT the pool's
// limiter at 51% (random-read delivery plateau is).
// dinv computed locally from deg (same rsqrtf as producer -> bit-identical);
// drops the 400 KB dinv read.
// ===========================================================================
#define P2_NODES 64
__global__ __launch_bounds__(256)
void gcn_gather_pool(const int* __restrict__ deg, const int* __restrict__ ell,
                     const unsigned short* __restrict__ ub,
                     const float* __restrict__ bias, const int* __restrict__ batch,
                     float* __restrict__ g, int N)
{
    const int grp  = threadIdx.x >> 5;
    const int lane = threadIdx.x & 31;
    const int n0   = blockIdx.x * P2_NODES + grp * 8;
    const ushort4* V4 = (const ushort4*)ub;

    float4 bj;
    bj.x = bias[lane * 4 + 0];
    bj.y = bias[lane * 4 + 1];
    bj.z = bias[lane * 4 + 2];
    bj.w = bias[lane * 4 + 3];

    float4 lsum = make_float4(0.f, 0.f, 0.f, 0.f);
    int prev = -1;

    for (int k = 0; k < 8; ++k) {
        int node = n0 + k;
        if (node >= N) break;
        int dn = deg[node];
        const int* row = ell + node * ELLW;
        float4 acc = dec4(V4[(size_t)node * 32 + lane]);   // self term u_i
        int e = 0;
        for (; e + 8 <= dn; e += 8) {
            int s0 = row[e + 0], s1 = row[e + 1], s2 = row[e + 2], s3 = row[e + 3];
            int s4 = row[e + 4], s5 = row[e + 5], s6 = row[e + 6], s7 = row[e + 7];
            float4 v0 = dec4(V4[(size_t)s0 * 32 + lane]);
            float4 v1 = dec4(V4[(size_t)s1 * 32 + lane]);
            float4 v2 = dec4(V4[(size_t)s2 * 32 + lane]);
            float4 v3 = dec4(V4[(size_t)s3 * 32 + lane]);
            float4 v4 = dec4(V4[(size_t)s4 * 32 + lane]);
            float4 v5 = dec4(V4[(size_t)s5 * 32 + lane]);
            float4 v6 = dec4(V4[(size_t)s6 * 32 + lane]);
            float4 v7 = dec4(V4[(size_t)s7 * 32 + lane]);
            acc.x += (v0.x + v1.x + v2.x + v3.x) + (v4.x + v5.x + v6.x + v7.x);
            acc.y += (v0.y + v1.y + v2.y + v3.y) + (v4.y + v5.y + v6.y + v7.y);
            acc.z += (v0.z + v1.z + v2.z + v3.z) + (v4.z + v5.z + v6.z + v7.z);
            acc.w += (v0.w + v1.w + v2.w + v3.w) + (v4.w + v5.w + v6.w + v7.w);
        }
        for (; e + 4 <= dn; e += 4) {
            int s0 = row[e + 0], s1 = row[e + 1], s2 = row[e + 2], s3 = row[e + 3];
            float4 v0 = dec4(V4[(size_t)s0 * 32 + lane]);
            float4 v1 = dec4(V4[(size_t)s1 * 32 + lane]);
            float4 v2 = dec4(V4[(size_t)s2 * 32 + lane]);
            float4 v3 = dec4(V4[(size_t)s3 * 32 + lane]);
            acc.x += v0.x + v1.x + v2.x + v3.x;
            acc.y += v0.y + v1.y + v2.y + v3.y;
            acc.z += v0.z + v1.z + v2.z + v3.z;
            acc.w += v0.w + v1.w + v2.w + v3.w;
        }
        for (; e < dn; ++e) {
            int s = row[e];
            float4 v = dec4(V4[(size_t)s * 32 + lane]);
            acc.x += v.x; acc.y += v.y; acc.z += v.z; acc.w += v.w;
        }
        float di = rsqrtf((float)dn + 1.0f);
        float4 h;
        h.x = fmaxf(fmaf(di, acc.x, bj.x), 0.f);
        h.y = fmaxf(fmaf(di, acc.y, bj.y), 0.f);
        h.z = fmaxf(fmaf(di, acc.z, bj.z), 0.f);
        h.w = fmaxf(fmaf(di, acc.w, bj.w), 0.f);

        int b = batch[node];
        if (b != prev) {
            if (prev >= 0) {
                float* gp = &g[(size_t)prev * DIM + lane * 4];
                atomicAdd(gp + 0, lsum.x);
                atomicAdd(gp + 1, lsum.y);
                atomicAdd(gp + 2, lsum.z);
                atomicAdd(gp + 3, lsum.w);
            }
            lsum = make_float4(0.f, 0.f, 0.f, 0.f);
            prev = b;
        }
        lsum.x += h.x; lsum.y += h.y; lsum.z += h.z; lsum.w += h.w;
    }
    if (prev >= 0) {
        float* gp = &g[(size_t)prev * DIM + lane * 4];
        atomicAdd(gp + 0, lsum.x);
        atomicAdd(gp + 1, lsum.y);
        atomicAdd(gp + 2, lsum.z);
        atomicAdd(gp + 3, lsum.w);
    }
}

// ===========================================================================
// Head: out[gid] = relu(g[gid] @ lin1_w + b1) @ lin2_w + b2
// ===========================================================================
__global__ __launch_bounds__(128)
void head_kernel(const float* __restrict__ g, const float* __restrict__ w1,
                 const float* __restrict__ b1, const float* __restrict__ w2,
                 const float* __restrict__ b2, float* __restrict__ out)
{
    __shared__ float gs[DIM];
    __shared__ float red[6];
    int gid = blockIdx.x;
    int t = threadIdx.x;

    gs[t] = g[(size_t)gid * DIM + t];
    __syncthreads();

    float acc = b1[t];
#pragma unroll
    for (int k = 0; k < DIM; ++k) acc = fmaf(gs[k], w1[k * DIM + t], acc);
    float h = fmaxf(acc, 0.f);

    float c0 = h * w2[t * 3 + 0];
    float c1 = h * w2[t * 3 + 1];
    float c2 = h * w2[t * 3 + 2];
#pragma unroll
    for (int off = 32; off >= 1; off >>= 1) {
        c0 += __shfl_down(c0, off);
        c1 += __shfl_down(c1, off);
        c2 += __shfl_down(c2, off);
    }
    int wave = t >> 6;
    if ((t & 63) == 0) {
        red[wave * 3 + 0] = c0;
        red[wave * 3 + 1] = c1;
        red[wave * 3 + 2] = c2;
    }
    __syncthreads();
    if (t == 0) {
        out[(size_t)gid * 3 + 0] = red[0] + red[3] + b2[0];
        out[(size_t)gid * 3 + 1] = red[1] + red[4] + b2[1];
        out[(size_t)gid * 3 + 2] = red[2] + red[5] + b2[2];
    }
}

// ===========================================================================
extern "C" void kernel_launch(void* const* d_in, const int* in_sizes, int n_in,
                              void* d_out, int out_size, void* d_ws, size_t ws_size,
                              hipStream_t stream)
{
    const float* x       = (const float*)d_in[0];
    const int*   eidx    = (const int*)d_in[1];
    const int*   batch   = (const int*)d_in[2];
    const float* gin_w1  = (const float*)d_in[3];
    const float* gin_b1  = (const float*)d_in[4];
    const float* gin_w2  = (const float*)d_in[5];
    const float* gin_b2  = (const float*)d_in[6];
    const float* gcn_w   = (const float*)d_in[7];
    const float* gcn_b   = (const float*)d_in[8];
    const float* lin1_w  = (const float*)d_in[9];
    const float* lin1_b  = (const float*)d_in[10];
    const float* lin2_w  = (const float*)d_in[11];
    const float* lin2_b  = (const float*)d_in[12];

    const int* src = eidx;
    const int* dst = eidx + N_EDGES;

    // workspace carve (256B aligned); total ~105 MB
    const size_t NBH = (size_t)N_NODES * DIM * sizeof(unsigned short); // 25.6 MB
    const size_t WTB = (size_t)DIM * DIM * sizeof(unsigned short);     // 32 KB
    char* base = (char*)d_ws;
    size_t off = 0;
    auto carve = [&](size_t bytes) {
        char* p = base + off;
        off = (off + bytes + 255) & ~(size_t)255;
        return p;
    };
    unsigned short* xb  = (unsigned short*)carve(NBH);  // x in bf16
    unsigned short* hb  = (unsigned short*)carve(NBH);  // gathered H in bf16
    unsigned short* ub  = (unsigned short*)carve(NBH);  // u in bf16
    unsigned short* w1t = (unsigned short*)carve(WTB);  // gin_w1^T bf16
    unsigned short* w2t = (unsigned short*)carve(WTB);
    unsigned short* w3t = (unsigned short*)carve(WTB);
    int*   cursor = (int*)  carve(N_NODES * sizeof(int));              // -> deg
    int*   ell    = (int*)  carve((size_t)N_NODES * ELLW * sizeof(int)); // 25.6MB
    float* dinv   = (float*)carve(N_NODES * sizeof(float));
    float* g      = (float*)carve((size_t)N_GRAPHS * DIM * sizeof(float));

    const int ngrid = (N_NODES + 7) / 8;
    const int mgrid = (N_NODES + MLP_ROWS - 1) / MLP_ROWS;
    const int pgrid = (N_NODES + P2_NODES - 1) / P2_NODES;

    // ---- casts + weight transpose + cursor zeroing (one dispatch) ----
    cast_bf16<<<(N_NODES * DIM / 8 + 255) / 256, 256, 0, stream>>>(
        x, xb, cursor, gin_w1, w1t, gin_w2, w2t, gcn_w, w3t,
        N_NODES * DIM / 8);

    // ---- ELL build (also zeroes g); cursor ends as degree ----
    ell_fill<<<FILL_RANGES * 128, 256, 0, stream>>>(src, dst, cursor, ell,
                                                    g, N_EDGES);

    // ---- GIN gather (bf16 in/out, fp32 acc); also writes dinv ----
    ell_gather_bb<<<ngrid, 256, 0, stream>>>(cursor, ell, xb, hb, dinv, N_NODES);

    // ---- fused 3-layer MLP via MFMA (W staged in LDS) -> u (bf16) ----
    mlp3_mfma<<<mgrid, 256, 0, stream>>>(hb, w1t, gin_b1, w2t, gin_b2,
                                         w3t, dinv, ub, N_NODES);

    // ---- fused GCN gather (bf16) + finalize + pool -> g ----
    gcn_gather_pool<<<pgrid, 256, 0, stream>>>(cursor, ell, ub, gcn_b,
                                               batch, g, N_NODES);

    // ---- head ----
    head_kernel<<<N_GRAPHS, 128, 0, stream>>>(
        g, lin1_w, lin1_b, lin2_w, lin2_b, (float*)d_out);
}

// Round 4
// 332.586 us; speedup vs baseline: 1.2805x; 1.0927x over previous
//
#include <hip/hip_runtime.h>
#include <hip/hip_bf16.h>
#include <hip/hip_fp8.h>

// Problem constants (match reference)
#define N_NODES  100000
#define N_EDGES  1600000
#define N_GRAPHS 2048
#define DIM      128   // IN_DIM == HIDDEN == 128
#define ELLW     64    // padded edges/node; deg ~ Poisson(16), max ~40

// ---- bf16 helpers (RNE encode, bit-shift decode) --------------------------
__device__ __forceinline__ unsigned short f2b(float f) {
    unsigned u = __float_as_uint(f);
    u += 0x7FFFu + ((u >> 16) & 1u);
    return (unsigned short)(u >> 16);
}
__device__ __forceinline__ float b2f(unsigned short h) {
    return __uint_as_float(((unsigned)h) << 16);
}
__device__ __forceinline__ float4 dec4(ushort4 h) {
    return make_float4(b2f(h.x), b2f(h.y), b2f(h.z), b2f(h.w));
}

// ---- fp8 e4m3 (OCP) helpers: ub stored as fp8 with fixed x64 pre-scale ----
// Halves gather-2's random-row payload: 256B -> 128B = 1 cache line/row.
#define UB_SCALE     64.0f
#define UB_INVSCALE  0.015625f

__device__ __forceinline__ unsigned char f_to_fp8(float x) {
#if __has_builtin(__builtin_amdgcn_cvt_pk_fp8_f32)
    return (unsigned char)(__builtin_amdgcn_cvt_pk_fp8_f32(x, x, 0, false) & 0xff);
#else
    __hip_fp8_e4m3 q(x);
    return q.__x;
#endif
}
__device__ __forceinline__ float4 fp8x4_to_f4(unsigned p) {
#if __has_builtin(__builtin_amdgcn_cvt_f32_fp8)
    return make_float4(__builtin_amdgcn_cvt_f32_fp8((int)p, 0),
                       __builtin_amdgcn_cvt_f32_fp8((int)p, 1),
                       __builtin_amdgcn_cvt_f32_fp8((int)p, 2),
                       __builtin_amdgcn_cvt_f32_fp8((int)p, 3));
#else
    __hip_fp8_e4m3 a, b, c, d;
    a.__x = (unsigned char)(p & 0xff);
    b.__x = (unsigned char)((p >> 8) & 0xff);
    c.__x = (unsigned char)((p >> 16) & 0xff);
    d.__x = (unsigned char)((p >> 24) & 0xff);
    return make_float4((float)a, (float)b, (float)c, (float)d);
#endif
}

// MFMA fragment types (gfx950, 16x16x32 bf16: 8 bf16 in / 4 fp32 acc)
typedef __attribute__((ext_vector_type(8))) short bfrag;
typedef __attribute__((ext_vector_type(4))) float ffrag;

// ===========================================================================
// MERGED cast + ELL-fill (round-4): the two stages are independent once
// cursor is zeroed by hipMemsetAsync, so one heterogeneous dispatch overlaps
// fill's atomic/scatter phase with cast's streaming. Both roles are LDS-free.
//   blocks [0, 1024):      ELL fill (XCD-range-partitioned) + zero g[]
//   blocks [1024, 1024+6250): fp32->bf16 cast of x + weight transposes
// ===========================================================================
#define FILL_RANGES 8
#define FILL_RSIZE  (N_NODES / FILL_RANGES)   // 12500 exact
#define CF_FILL_BLOCKS 1024
#define CF_CAST_BLOCKS 6250                   // 1.6M elems / 256

__global__ __launch_bounds__(256)
void cast_fill(const float* __restrict__ in, unsigned short* __restrict__ out,
               const float* __restrict__ Wa, unsigned short* __restrict__ Ta,
               const float* __restrict__ Wb, unsigned short* __restrict__ Tb,
               const float* __restrict__ Wc, unsigned short* __restrict__ Tc,
               const int* __restrict__ src, const int* __restrict__ dst,
               int* __restrict__ cursor, int* __restrict__ ell,
               float* __restrict__ g, int E, int n8)
{
    const int bid = blockIdx.x;
    const int t   = threadIdx.x;

    if (bid < CF_FILL_BLOCKS) {
        // ---- fill role (identical logic to prior ell_fill) ----
        int gid = bid * 256 + t;              // 1024*256 = exactly |g|
        g[gid] = 0.f;

        const int r = bid & (FILL_RANGES - 1);
        const int s = bid >> 3;
        const int nslice = CF_FILL_BLOCKS >> 3;
        const unsigned lo = (unsigned)(r * FILL_RSIZE);
        const int stride = nslice * 256 * 4;

        for (int e0 = (s * 256 + t) * 4; e0 < E; e0 += stride) {
            int4 d  = *(const int4*)&dst[e0];
            int4 sv = *(const int4*)&src[e0];
            if ((unsigned)(d.x - lo) < (unsigned)FILL_RSIZE) {
                int p = atomicAdd(&cursor[d.x], 1); ell[d.x * ELLW + p] = sv.x;
            }
            if ((unsigned)(d.y - lo) < (unsigned)FILL_RSIZE) {
                int p = atomicAdd(&cursor[d.y], 1); ell[d.y * ELLW + p] = sv.y;
            }
            if ((unsigned)(d.z - lo) < (unsigned)FILL_RSIZE) {
                int p = atomicAdd(&cursor[d.z], 1); ell[d.z * ELLW + p] = sv.z;
            }
            if ((unsigned)(d.w - lo) < (unsigned)FILL_RSIZE) {
                int p = atomicAdd(&cursor[d.w], 1); ell[d.w * ELLW + p] = sv.w;
            }
        }
    } else {
        // ---- cast role ----
        int i = (bid - CF_FILL_BLOCKS) * 256 + t;
        if (i < 3 * DIM * DIM) {
            int which = i >> 14;              // 16384 elems per weight
            int idx   = i & (DIM * DIM - 1);
            const float* W = (which == 0) ? Wa : (which == 1) ? Wb : Wc;
            unsigned short* T = (which == 0) ? Ta : (which == 1) ? Tb : Tc;
            int k = idx >> 7, n = idx & 127;
            T[n * DIM + k] = f2b(W[idx]);
        }
        if (i >= n8) return;
        const float4* in4 = (const float4*)in;
        float4 a = in4[i * 2 + 0];
        float4 b = in4[i * 2 + 1];
        uint4 q;
        q.x = (unsigned)f2b(a.x) | ((unsigned)f2b(a.y) << 16);
        q.y = (unsigned)f2b(a.z) | ((unsigned)f2b(a.w) << 16);
        q.z = (unsigned)f2b(b.x) | ((unsigned)f2b(b.y) << 16);
        q.w = (unsigned)f2b(b.z) | ((unsigned)f2b(b.w) << 16);
        ((uint4*)out)[i] = q;
    }
}

// ===========================================================================
// bf16 ELL gather -> bf16 out: Out[i] = Vb[i] + sum_{e<deg[i]} Vb[ell[i][e]]
// (fp32 accumulate). Lane 0 also writes dinv[i] = rsqrt(deg+1).
// One node per 32-lane group, ushort4 per lane, x8/x4/x1 unroll tiers.
// 12500-block oversubscription is REQUIRED for the random-read delivery
// plateau (round-1/2 lesson: fused 1563-block variants dropped to 1.3-1.7
// TB/s and regressed +29/+59 us).
// ===========================================================================
__global__ __launch_bounds__(256)
void ell_gather_bb(const int* __restrict__ deg, const int* __restrict__ ell,
                   const unsigned short* __restrict__ Vb,
                   unsigned short* __restrict__ Out,
                   float* __restrict__ dinv, int N)
{
    int node = blockIdx.x * 8 + (threadIdx.x >> 5);
    int lane = threadIdx.x & 31;
    if (node >= N) return;
    int dn = deg[node];
    if (lane == 0) dinv[node] = rsqrtf((float)dn + 1.0f);
    const int* row = ell + node * ELLW;
    const ushort4* V4 = (const ushort4*)Vb;
    float4 acc = dec4(V4[(size_t)node * 32 + lane]);   // self term
    int e = 0;
    for (; e + 8 <= dn; e += 8) {
        int s0 = row[e + 0], s1 = row[e + 1], s2 = row[e + 2], s3 = row[e + 3];
        int s4 = row[e + 4], s5 = row[e + 5], s6 = row[e + 6], s7 = row[e + 7];
        float4 v0 = dec4(V4[(size_t)s0 * 32 + lane]);
        float4 v1 = dec4(V4[(size_t)s1 * 32 + lane]);
        float4 v2 = dec4(V4[(size_t)s2 * 32 + lane]);
        float4 v3 = dec4(V4[(size_t)s3 * 32 + lane]);
        float4 v4 = dec4(V4[(size_t)s4 * 32 + lane]);
        float4 v5 = dec4(V4[(size_t)s5 * 32 + lane]);
        float4 v6 = dec4(V4[(size_t)s6 * 32 + lane]);
        float4 v7 = dec4(V4[(size_t)s7 * 32 + lane]);
        acc.x += (v0.x + v1.x + v2.x + v3.x) + (v4.x + v5.x + v6.x + v7.x);
        acc.y += (v0.y + v1.y + v2.y + v3.y) + (v4.y + v5.y + v6.y + v7.y);
        acc.z += (v0.z + v1.z + v2.z + v3.z) + (v4.z + v5.z + v6.z + v7.z);
        acc.w += (v0.w + v1.w + v2.w + v3.w) + (v4.w + v5.w + v6.w + v7.w);
    }
    for (; e + 4 <= dn; e += 4) {
        int s0 = row[e + 0], s1 = row[e + 1], s2 = row[e + 2], s3 = row[e + 3];
        float4 v0 = dec4(V4[(size_t)s0 * 32 + lane]);
        float4 v1 = dec4(V4[(size_t)s1 * 32 + lane]);
        float4 v2 = dec4(V4[(size_t)s2 * 32 + lane]);
        float4 v3 = dec4(V4[(size_t)s3 * 32 + lane]);
        acc.x += v0.x + v1.x + v2.x + v3.x;
        acc.y += v0.y + v1.y + v2.y + v3.y;
        acc.z += v0.z + v1.z + v2.z + v3.z;
        acc.w += v0.w + v1.w + v2.w + v3.w;
    }
    for (; e < dn; ++e) {
        int s = row[e];
        float4 v = dec4(V4[(size_t)s * 32 + lane]);
        acc.x += v.x; acc.y += v.y; acc.z += v.z; acc.w += v.w;
    }
    ushort4 o;
    o.x = f2b(acc.x); o.y = f2b(acc.y); o.z = f2b(acc.z); o.w = f2b(acc.w);
    ((ushort4*)Out)[(size_t)node * 32 + lane] = o;
}

// ===========================================================================
// Fused 3-layer MLP via MFMA 16x16x32 bf16 (fp32 accumulate), W staged in LDS
// (round-10 win; round-2 lesson: global-B MFMA is latency-bound, keep LDS).
// Block = 256 thr = 4 waves; 64 rows; wave w owns 16 rows (row-parallel).
// LDS: Hb 17.4K + Ws 34.8K = 52.2K -> 3 blocks/CU.
// Epilogue now writes ub as fp8-e4m3 (x64 pre-scale) -> halves gather-2 rows.
// A-frag: A[m=lane&15][k=quad*8+j]; B-frag from Ws[n][k];
// C/D: col=lane&15, row=quad*4+reg (verified layouts, m89/m120).
// ===========================================================================
#define MLP_ROWS 64
#define HBST     136

__global__ __launch_bounds__(256)
void mlp3_mfma(const unsigned short* __restrict__ Hg,
               const unsigned short* __restrict__ w1t, const float* __restrict__ b1,
               const unsigned short* __restrict__ w2t, const float* __restrict__ b2,
               const unsigned short* __restrict__ w3t, const float* __restrict__ dinv,
               unsigned char* __restrict__ ub_out, int N)
{
    __shared__ unsigned short Hb[MLP_ROWS][HBST];
    __shared__ unsigned short Ws[DIM][HBST];

    const int tid  = threadIdx.x;
    const int wave = tid >> 6;        // 0..3
    const int lane = tid & 63;
    const int row0 = blockIdx.x * MLP_ROWS;

    // ---- load H tile (coalesced uint4 = 8 bf16): 1024 x 16 B, 4/thread ----
#pragma unroll
    for (int l = 0; l < 4; ++l) {
        int f  = tid + l * 256;       // 0..1023
        int r  = f >> 4;              // 0..63
        int c8 = (f & 15) << 3;       // 0,8,...,120
        int gr = row0 + r;
        uint4 v = make_uint4(0u, 0u, 0u, 0u);
        if (gr < N) v = *(const uint4*)&Hg[(size_t)gr * DIM + c8];
        *(uint4*)&Hb[r][c8] = v;
    }

    const int m0 = wave * 16;
    const int qa = lane >> 4;         // quad 0..3
    const int la = lane & 15;

    for (int layer = 0; layer < 3; ++layer) {
        const unsigned short* __restrict__ Wt =
            (layer == 0) ? w1t : (layer == 1) ? w2t : w3t;

        // ---- stage Wt[128][128] -> Ws: 2048 uint4, 8/thread (L2-hot) ----
        __syncthreads();   // prior-layer Ws reads (and layer-0 H load) done
#pragma unroll
        for (int l = 0; l < 8; ++l) {
            int f  = tid + l * 256;   // 0..2047
            int r  = f >> 4;          // 0..127
            int c8 = (f & 15) << 3;
            *(uint4*)&Ws[r][c8] = *(const uint4*)&Wt[(size_t)r * DIM + c8];
        }
        __syncthreads();

        // A fragments for this wave's 16 rows, all K (4 chunks of 32)
        bfrag afr[4];
#pragma unroll
        for (int kc = 0; kc < 4; ++kc)
            afr[kc] = *(const bfrag*)&Hb[m0 + la][kc * 32 + qa * 8];

        if (layer < 2) {
            const float* bias = (layer == 0) ? b1 : b2;
#pragma unroll
            for (int nt = 0; nt < 8; ++nt) {
                const int n0 = nt * 16;
                ffrag acc = {0.f, 0.f, 0.f, 0.f};
#pragma unroll
                for (int kc = 0; kc < 4; ++kc) {
                    bfrag bfr = *(const bfrag*)&Ws[n0 + la][kc * 32 + qa * 8];
                    acc = __builtin_amdgcn_mfma_f32_16x16x32_bf16(afr[kc], bfr, acc, 0, 0, 0);
                }
                float bn = bias[n0 + la];
#pragma unroll
                for (int r = 0; r < 4; ++r) {
                    float v = fmaxf(acc[r] + bn, 0.f);
                    Hb[m0 + qa * 4 + r][n0 + la] = f2b(v);
                }
            }
            // wave-private rows: program order suffices before next layer
        } else {
            float dv[4];
#pragma unroll
            for (int r = 0; r < 4; ++r) {
                int gr = row0 + m0 + qa * 4 + r;
                dv[r] = (gr < N) ? dinv[gr] * UB_SCALE : 0.f;
            }
#pragma unroll
            for (int nt = 0; nt < 8; ++nt) {
                const int n0 = nt * 16;
                ffrag acc = {0.f, 0.f, 0.f, 0.f};
#pragma unroll
                for (int kc = 0; kc < 4; ++kc) {
                    bfrag bfr = *(const bfrag*)&Ws[n0 + la][kc * 32 + qa * 8];
                    acc = __builtin_amdgcn_mfma_f32_16x16x32_bf16(afr[kc], bfr, acc, 0, 0, 0);
                }
#pragma unroll
                for (int r = 0; r < 4; ++r) {
                    int gr = row0 + m0 + qa * 4 + r;
                    if (gr < N)
                        ub_out[(size_t)gr * DIM + n0 + la] = f_to_fp8(dv[r] * acc[r]);
                }
            }
        }
    }
}

// ===========================================================================
// Fused GCN gather (fp8 u, ELL) + finalize + global_add_pool.
// ub rows are 128 B fp8 (x64 pre-scaled): each random neighbor row is now ONE
// 128B cache line (was two) -> both bytes and transactions halve vs bf16.
// Decode via hw v_cvt_f32_fp8; the 1/64 descale folds into di at finalize.
// P2_NODES=64 (8 sequential nodes per 32-lane group): round-13 showed 32
// doubles pool-atomic WRITE and regresses; keep.
// ===========================================================================
#define P2_NODES 64
__global__ __launch_bounds__(256)
void gcn_gather_pool(const int* __restrict__ deg, const int* __restrict__ ell,
                     const unsigned char* __restrict__ ub,
                     const float* __restrict__ bias, const int* __restrict__ batch,
                     float* __restrict__ g, int N)
{
    const int grp  = threadIdx.x >> 5;
    const int lane = threadIdx.x & 31;
    const int n0   = blockIdx.x * P2_NODES + grp * 8;
    const unsigned* U4 = (const unsigned*)ub;   // 32 x uint per 128B row

    float4 bj;
    bj.x = bias[lane * 4 + 0];
    bj.y = bias[lane * 4 + 1];
    bj.z = bias[lane * 4 + 2];
    bj.w = bias[lane * 4 + 3];

    float4 lsum = make_float4(0.f, 0.f, 0.f, 0.f);
    int prev = -1;

    for (int k = 0; k < 8; ++k) {
        int node = n0 + k;
        if (node >= N) break;
        int dn = deg[node];
        const int* row = ell + node * ELLW;
        float4 acc = fp8x4_to_f4(U4[(size_t)node * 32 + lane]);  // self term
        int e = 0;
        for (; e + 8 <= dn; e += 8) {
            int s0 = row[e + 0], s1 = row[e + 1], s2 = row[e + 2], s3 = row[e + 3];
            int s4 = row[e + 4], s5 = row[e + 5], s6 = row[e + 6], s7 = row[e + 7];
            unsigned w0 = U4[(size_t)s0 * 32 + lane];
            unsigned w1 = U4[(size_t)s1 * 32 + lane];
            unsigned w2 = U4[(size_t)s2 * 32 + lane];
            unsigned w3 = U4[(size_t)s3 * 32 + lane];
            unsigned w4 = U4[(size_t)s4 * 32 + lane];
            unsigned w5 = U4[(size_t)s5 * 32 + lane];
            unsigned w6 = U4[(size_t)s6 * 32 + lane];
            unsigned w7 = U4[(size_t)s7 * 32 + lane];
            float4 v0 = fp8x4_to_f4(w0);
            float4 v1 = fp8x4_to_f4(w1);
            float4 v2 = fp8x4_to_f4(w2);
            float4 v3 = fp8x4_to_f4(w3);
            float4 v4 = fp8x4_to_f4(w4);
            float4 v5 = fp8x4_to_f4(w5);
            float4 v6 = fp8x4_to_f4(w6);
            float4 v7 = fp8x4_to_f4(w7);
            acc.x += (v0.x + v1.x + v2.x + v3.x) + (v4.x + v5.x + v6.x + v7.x);
            acc.y += (v0.y + v1.y + v2.y + v3.y) + (v4.y + v5.y + v6.y + v7.y);
            acc.z += (v0.z + v1.z + v2.z + v3.z) + (v4.z + v5.z + v6.z + v7.z);
            acc.w += (v0.w + v1.w + v2.w + v3.w) + (v4.w + v5.w + v6.w + v7.w);
        }
        for (; e + 4 <= dn; e += 4) {
            int s0 = row[e + 0], s1 = row[e + 1], s2 = row[e + 2], s3 = row[e + 3];
            float4 v0 = fp8x4_to_f4(U4[(size_t)s0 * 32 + lane]);
            float4 v1 = fp8x4_to_f4(U4[(size_t)s1 * 32 + lane]);
            float4 v2 = fp8x4_to_f4(U4[(size_t)s2 * 32 + lane]);
            float4 v3 = fp8x4_to_f4(U4[(size_t)s3 * 32 + lane]);
            acc.x += v0.x + v1.x + v2.x + v3.x;
            acc.y += v0.y + v1.y + v2.y + v3.y;
            acc.z += v0.z + v1.z + v2.z + v3.z;
            acc.w += v0.w + v1.w + v2.w + v3.w;
        }
        for (; e < dn; ++e) {
            int s = row[e];
            float4 v = fp8x4_to_f4(U4[(size_t)s * 32 + lane]);
            acc.x += v.x; acc.y += v.y; acc.z += v.z; acc.w += v.w;
        }
        // descale (1/64) folded into di
        float di = rsqrtf((float)dn + 1.0f) * UB_INVSCALE;
        float4 h;
        h.x = fmaxf(fmaf(di, acc.x, bj.x), 0.f);
        h.y = fmaxf(fmaf(di, acc.y, bj.y), 0.f);
        h.z = fmaxf(fmaf(di, acc.z, bj.z), 0.f);
        h.w = fmaxf(fmaf(di, acc.w, bj.w), 0.f);

        int b = batch[node];
        if (b != prev) {
            if (prev >= 0) {
                float* gp = &g[(size_t)prev * DIM + lane * 4];
                atomicAdd(gp + 0, lsum.x);
                atomicAdd(gp + 1, lsum.y);
                atomicAdd(gp + 2, lsum.z);
                atomicAdd(gp + 3, lsum.w);
            }
            lsum = make_float4(0.f, 0.f, 0.f, 0.f);
            prev = b;
        }
        lsum.x += h.x; lsum.y += h.y; lsum.z += h.z; lsum.w += h.w;
    }
    if (prev >= 0) {
        float* gp = &g[(size_t)prev * DIM + lane * 4];
        atomicAdd(gp + 0, lsum.x);
        atomicAdd(gp + 1, lsum.y);
        atomicAdd(gp + 2, lsum.z);
        atomicAdd(gp + 3, lsum.w);
    }
}

// ===========================================================================
// Head: out[gid] = relu(g[gid] @ lin1_w + b1) @ lin2_w + b2
// ===========================================================================
__global__ __launch_bounds__(128)
void head_kernel(const float* __restrict__ g, const float* __restrict__ w1,
                 const float* __restrict__ b1, const float* __restrict__ w2,
                 const float* __restrict__ b2, float* __restrict__ out)
{
    __shared__ float gs[DIM];
    __shared__ float red[6];
    int gid = blockIdx.x;
    int t = threadIdx.x;

    gs[t] = g[(size_t)gid * DIM + t];
    __syncthreads();

    float acc = b1[t];
#pragma unroll
    for (int k = 0; k < DIM; ++k) acc = fmaf(gs[k], w1[k * DIM + t], acc);
    float h = fmaxf(acc, 0.f);

    float c0 = h * w2[t * 3 + 0];
    float c1 = h * w2[t * 3 + 1];
    float c2 = h * w2[t * 3 + 2];
#pragma unroll
    for (int off = 32; off >= 1; off >>= 1) {
        c0 += __shfl_down(c0, off);
        c1 += __shfl_down(c1, off);
        c2 += __shfl_down(c2, off);
    }
    int wave = t >> 6;
    if ((t & 63) == 0) {
        red[wave * 3 + 0] = c0;
        red[wave * 3 + 1] = c1;
        red[wave * 3 + 2] = c2;
    }
    __syncthreads();
    if (t == 0) {
        out[(size_t)gid * 3 + 0] = red[0] + red[3] + b2[0];
        out[(size_t)gid * 3 + 1] = red[1] + red[4] + b2[1];
        out[(size_t)gid * 3 + 2] = red[2] + red[5] + b2[2];
    }
}

// ===========================================================================
extern "C" void kernel_launch(void* const* d_in, const int* in_sizes, int n_in,
                              void* d_out, int out_size, void* d_ws, size_t ws_size,
                              hipStream_t stream)
{
    const float* x       = (const float*)d_in[0];
    const int*   eidx    = (const int*)d_in[1];
    const int*   batch   = (const int*)d_in[2];
    const float* gin_w1  = (const float*)d_in[3];
    const float* gin_b1  = (const float*)d_in[4];
    const float* gin_w2  = (const float*)d_in[5];
    const float* gin_b2  = (const float*)d_in[6];
    const float* gcn_w   = (const float*)d_in[7];
    const float* gcn_b   = (const float*)d_in[8];
    const float* lin1_w  = (const float*)d_in[9];
    const float* lin1_b  = (const float*)d_in[10];
    const float* lin2_w  = (const float*)d_in[11];
    const float* lin2_b  = (const float*)d_in[12];

    const int* src = eidx;
    const int* dst = eidx + N_EDGES;

    // workspace carve (256B aligned)
    const size_t NBH = (size_t)N_NODES * DIM * sizeof(unsigned short); // 25.6 MB
    const size_t NB8 = (size_t)N_NODES * DIM;                          // 12.8 MB
    const size_t WTB = (size_t)DIM * DIM * sizeof(unsigned short);     // 32 KB
    char* base = (char*)d_ws;
    size_t off = 0;
    auto carve = [&](size_t bytes) {
        char* p = base + off;
        off = (off + bytes + 255) & ~(size_t)255;
        return p;
    };
    unsigned short* xb  = (unsigned short*)carve(NBH);  // x in bf16
    unsigned short* hb  = (unsigned short*)carve(NBH);  // gathered H in bf16
    unsigned char*  ub8 = (unsigned char*) carve(NB8);  // u in fp8 e4m3 (x64)
    unsigned short* w1t = (unsigned short*)carve(WTB);  // gin_w1^T bf16
    unsigned short* w2t = (unsigned short*)carve(WTB);
    unsigned short* w3t = (unsigned short*)carve(WTB);
    int*   cursor = (int*)  carve(N_NODES * sizeof(int));              // -> deg
    int*   ell    = (int*)  carve((size_t)N_NODES * ELLW * sizeof(int)); // 25.6MB
    float* dinv   = (float*)carve(N_NODES * sizeof(float));
    float* g      = (float*)carve((size_t)N_GRAPHS * DIM * sizeof(float));

    const int ngrid = (N_NODES + 7) / 8;
    const int mgrid = (N_NODES + MLP_ROWS - 1) / MLP_ROWS;
    const int pgrid = (N_NODES + P2_NODES - 1) / P2_NODES;

    // ---- zero cursor, then merged cast + ELL-fill (one dispatch) ----
    hipMemsetAsync(cursor, 0, N_NODES * sizeof(int), stream);
    cast_fill<<<CF_FILL_BLOCKS + CF_CAST_BLOCKS, 256, 0, stream>>>(
        x, xb, gin_w1, w1t, gin_w2, w2t, gcn_w, w3t,
        src, dst, cursor, ell, g, N_EDGES, N_NODES * DIM / 8);

    // ---- GIN gather (bf16 in/out, fp32 acc); also writes dinv ----
    ell_gather_bb<<<ngrid, 256, 0, stream>>>(cursor, ell, xb, hb, dinv, N_NODES);

    // ---- fused 3-layer MLP via MFMA (W staged in LDS) -> u (fp8) ----
    mlp3_mfma<<<mgrid, 256, 0, stream>>>(hb, w1t, gin_b1, w2t, gin_b2,
                                         w3t, dinv, ub8, N_NODES);

    // ---- fused GCN gather (fp8) + finalize + pool -> g ----
    gcn_gather_pool<<<pgrid, 256, 0, stream>>>(cursor, ell, ub8, gcn_b,
                                               batch, g, N_NODES);

    // ---- head ----
    head_kernel<<<N_GRAPHS, 128, 0, stream>>>(
        g, lin1_w, lin1_b, lin2_w, lin2_b, (float*)d_out);
}

// Round 5
// 310.645 us; speedup vs baseline: 1.3709x; 1.0706x over previous
//
#include <hip/hip_runtime.h>
#include <hip/hip_bf16.h>
#include <hip/hip_fp8.h>

// Problem constants (match reference)
#define N_NODES  100000
#define N_EDGES  1600000
#define N_GRAPHS 2048
#define DIM      128   // IN_DIM == HIDDEN == 128
#define ELLW     64    // padded edges/node; deg ~ Poisson(16), max ~40

// ---- bf16 helpers (RNE encode, bit-shift decode) --------------------------
__device__ __forceinline__ unsigned short f2b(float f) {
    unsigned u = __float_as_uint(f);
    u += 0x7FFFu + ((u >> 16) & 1u);
    return (unsigned short)(u >> 16);
}
__device__ __forceinline__ float b2f(unsigned short h) {
    return __uint_as_float(((unsigned)h) << 16);
}
__device__ __forceinline__ float4 dec4(ushort4 h) {
    return make_float4(b2f(h.x), b2f(h.y), b2f(h.z), b2f(h.w));
}

// ---- fp8 e4m3 (OCP) helpers: ub stored as fp8 with fixed x64 pre-scale ----
// (round-4 win: halves gather-2's random-row payload to 1 cache line/row)
#define UB_SCALE     64.0f
#define UB_INVSCALE  0.015625f

__device__ __forceinline__ unsigned char f_to_fp8(float x) {
#if __has_builtin(__builtin_amdgcn_cvt_pk_fp8_f32)
    return (unsigned char)(__builtin_amdgcn_cvt_pk_fp8_f32(x, x, 0, false) & 0xff);
#else
    __hip_fp8_e4m3 q(x);
    return q.__x;
#endif
}
__device__ __forceinline__ float4 fp8x4_to_f4(unsigned p) {
#if __has_builtin(__builtin_amdgcn_cvt_f32_fp8)
    return make_float4(__builtin_amdgcn_cvt_f32_fp8((int)p, 0),
                       __builtin_amdgcn_cvt_f32_fp8((int)p, 1),
                       __builtin_amdgcn_cvt_f32_fp8((int)p, 2),
                       __builtin_amdgcn_cvt_f32_fp8((int)p, 3));
#else
    __hip_fp8_e4m3 a, b, c, d;
    a.__x = (unsigned char)(p & 0xff);
    b.__x = (unsigned char)((p >> 8) & 0xff);
    c.__x = (unsigned char)((p >> 16) & 0xff);
    d.__x = (unsigned char)((p >> 24) & 0xff);
    return make_float4((float)a, (float)b, (float)c, (float)d);
#endif
}

// ---- int8 decode (sign-extend bytes); v_bfe_i32 + v_cvt_f32_i32 ----------
__device__ __forceinline__ float4 i8x4_to_f4(unsigned w) {
    return make_float4((float)((int)(w << 24) >> 24),
                       (float)((int)(w << 16) >> 24),
                       (float)((int)(w <<  8) >> 24),
                       (float)(((int)w) >> 24));
}

// MFMA fragment types (gfx950, 16x16x32 bf16: 8 bf16 in / 4 fp32 acc)
typedef __attribute__((ext_vector_type(8))) short bfrag;
typedef __attribute__((ext_vector_type(4))) float ffrag;

// ===========================================================================
// MERGED cast + ELL-fill. Roles by blockIdx:
//   [0, 1024):          ELL fill (XCD-range-partitioned) + zero g[]
//   [1024, 1024+12500): x row-quantize to int8 + per-row scale (32 lanes/row)
//   [13524, 13524+192): weight transposes fp32 -> bf16^T
// Round-5: x stored as int8 with per-row absmax scale -> gather-1 neighbor
// rows become ONE 128B cache line (round-4 proved transaction-bound: the
// same change took gcn_gather 82->~45 us). int8-per-row RMS err ~0.7% vs
// bf16's 0.4% (fp8's 3.6% is too hot for the pre-MLP path).
// ===========================================================================
#define FILL_RANGES 8
#define FILL_RSIZE  (N_NODES / FILL_RANGES)   // 12500 exact
#define CF_FILL_BLOCKS 1024
#define CF_ROW_BLOCKS  ((N_NODES + 7) / 8)    // 12500
#define CF_WT_BLOCKS   192                    // 49152 threads

__global__ __launch_bounds__(256)
void cast_fill(const float* __restrict__ in,
               unsigned* __restrict__ X8, float* __restrict__ xs,
               const float* __restrict__ Wa, unsigned short* __restrict__ Ta,
               const float* __restrict__ Wb, unsigned short* __restrict__ Tb,
               const float* __restrict__ Wc, unsigned short* __restrict__ Tc,
               const int* __restrict__ src, const int* __restrict__ dst,
               int* __restrict__ cursor, int* __restrict__ ell,
               float* __restrict__ g, int E)
{
    const int bid = blockIdx.x;
    const int t   = threadIdx.x;

    if (bid < CF_FILL_BLOCKS) {
        // ---- fill role ----
        int gid = bid * 256 + t;              // 1024*256 = exactly |g|
        g[gid] = 0.f;

        const int r = bid & (FILL_RANGES - 1);
        const int s = bid >> 3;
        const int nslice = CF_FILL_BLOCKS >> 3;
        const unsigned lo = (unsigned)(r * FILL_RSIZE);
        const int stride = nslice * 256 * 4;

        for (int e0 = (s * 256 + t) * 4; e0 < E; e0 += stride) {
            int4 d  = *(const int4*)&dst[e0];
            int4 sv = *(const int4*)&src[e0];
            if ((unsigned)(d.x - lo) < (unsigned)FILL_RSIZE) {
                int p = atomicAdd(&cursor[d.x], 1); ell[d.x * ELLW + p] = sv.x;
            }
            if ((unsigned)(d.y - lo) < (unsigned)FILL_RSIZE) {
                int p = atomicAdd(&cursor[d.y], 1); ell[d.y * ELLW + p] = sv.y;
            }
            if ((unsigned)(d.z - lo) < (unsigned)FILL_RSIZE) {
                int p = atomicAdd(&cursor[d.z], 1); ell[d.z * ELLW + p] = sv.z;
            }
            if ((unsigned)(d.w - lo) < (unsigned)FILL_RSIZE) {
                int p = atomicAdd(&cursor[d.w], 1); ell[d.w * ELLW + p] = sv.w;
            }
        }
    } else if (bid < CF_FILL_BLOCKS + CF_ROW_BLOCKS) {
        // ---- x row-quantize role: 8 rows/block, 32 lanes/row ----
        const int grp  = t >> 5;
        const int lane = t & 31;
        int node = (bid - CF_FILL_BLOCKS) * 8 + grp;
        if (node >= N_NODES) return;
        float4 v = ((const float4*)(in + (size_t)node * DIM))[lane];
        float am = fmaxf(fmaxf(fabsf(v.x), fabsf(v.y)),
                         fmaxf(fabsf(v.z), fabsf(v.w)));
#pragma unroll
        for (int o = 16; o >= 1; o >>= 1)
            am = fmaxf(am, __shfl_xor(am, o, 32));
        am = fmaxf(am, 1e-20f);
        float inv = 127.0f / am;
        int qx = (int)rintf(v.x * inv) & 255;
        int qy = (int)rintf(v.y * inv) & 255;
        int qz = (int)rintf(v.z * inv) & 255;
        int qw = (int)rintf(v.w * inv) & 255;
        unsigned p = (unsigned)qx | ((unsigned)qy << 8) |
                     ((unsigned)qz << 16) | ((unsigned)qw << 24);
        X8[(size_t)node * 32 + lane] = p;
        if (lane == 0) xs[node] = am * (1.0f / 127.0f);
    } else {
        // ---- weight transpose role ----
        int i = (bid - CF_FILL_BLOCKS - CF_ROW_BLOCKS) * 256 + t;
        if (i >= 3 * DIM * DIM) return;
        int which = i >> 14;              // 16384 elems per weight
        int idx   = i & (DIM * DIM - 1);
        const float* W = (which == 0) ? Wa : (which == 1) ? Wb : Wc;
        unsigned short* T = (which == 0) ? Ta : (which == 1) ? Tb : Tc;
        int k = idx >> 7, n = idx & 127;
        T[n * DIM + k] = f2b(W[idx]);
    }
}

// ===========================================================================
// int8 ELL gather -> bf16 out: Out[i] = x[i] + sum_{e<deg[i]} x[ell[i][e]]
// (fp32 accumulate; x decoded as int8 * per-row scale). Lane 0 also writes
// dinv[i] = rsqrt(deg+1). One node per 32-lane group: neighbor row = ONE
// 128B line (uint/lane). Scale loads are group-uniform 4B (L2-hot, 400KB).
// 12500-block oversubscription REQUIRED (round-1/2 lesson).
// ===========================================================================
__global__ __launch_bounds__(256)
void ell_gather_i8(const int* __restrict__ deg, const int* __restrict__ ell,
                   const unsigned* __restrict__ X8, const float* __restrict__ xs,
                   unsigned short* __restrict__ Out,
                   float* __restrict__ dinv, int N)
{
    int node = blockIdx.x * 8 + (threadIdx.x >> 5);
    int lane = threadIdx.x & 31;
    if (node >= N) return;
    int dn = deg[node];
    if (lane == 0) dinv[node] = rsqrtf((float)dn + 1.0f);
    const int* row = ell + node * ELLW;

    float4 acc = make_float4(0.f, 0.f, 0.f, 0.f);
    {   // self term
        float c = xs[node];
        float4 v = i8x4_to_f4(X8[(size_t)node * 32 + lane]);
        acc.x = v.x * c; acc.y = v.y * c; acc.z = v.z * c; acc.w = v.w * c;
    }
    int e = 0;
    for (; e + 8 <= dn; e += 8) {
        int s0 = row[e + 0], s1 = row[e + 1], s2 = row[e + 2], s3 = row[e + 3];
        int s4 = row[e + 4], s5 = row[e + 5], s6 = row[e + 6], s7 = row[e + 7];
        float c0 = xs[s0], c1 = xs[s1], c2 = xs[s2], c3 = xs[s3];
        float c4 = xs[s4], c5 = xs[s5], c6 = xs[s6], c7 = xs[s7];
        unsigned w0 = X8[(size_t)s0 * 32 + lane];
        unsigned w1 = X8[(size_t)s1 * 32 + lane];
        unsigned w2 = X8[(size_t)s2 * 32 + lane];
        unsigned w3 = X8[(size_t)s3 * 32 + lane];
        unsigned w4 = X8[(size_t)s4 * 32 + lane];
        unsigned w5 = X8[(size_t)s5 * 32 + lane];
        unsigned w6 = X8[(size_t)s6 * 32 + lane];
        unsigned w7 = X8[(size_t)s7 * 32 + lane];
        float4 v0 = i8x4_to_f4(w0);
        float4 v1 = i8x4_to_f4(w1);
        float4 v2 = i8x4_to_f4(w2);
        float4 v3 = i8x4_to_f4(w3);
        float4 v4 = i8x4_to_f4(w4);
        float4 v5 = i8x4_to_f4(w5);
        float4 v6 = i8x4_to_f4(w6);
        float4 v7 = i8x4_to_f4(w7);
        acc.x = fmaf(v0.x, c0, fmaf(v1.x, c1, fmaf(v2.x, c2, fmaf(v3.x, c3, acc.x))));
        acc.y = fmaf(v0.y, c0, fmaf(v1.y, c1, fmaf(v2.y, c2, fmaf(v3.y, c3, acc.y))));
        acc.z = fmaf(v0.z, c0, fmaf(v1.z, c1, fmaf(v2.z, c2, fmaf(v3.z, c3, acc.z))));
        acc.w = fmaf(v0.w, c0, fmaf(v1.w, c1, fmaf(v2.w, c2, fmaf(v3.w, c3, acc.w))));
        acc.x = fmaf(v4.x, c4, fmaf(v5.x, c5, fmaf(v6.x, c6, fmaf(v7.x, c7, acc.x))));
        acc.y = fmaf(v4.y, c4, fmaf(v5.y, c5, fmaf(v6.y, c6, fmaf(v7.y, c7, acc.y))));
        acc.z = fmaf(v4.z, c4, fmaf(v5.z, c5, fmaf(v6.z, c6, fmaf(v7.z, c7, acc.z))));
        acc.w = fmaf(v4.w, c4, fmaf(v5.w, c5, fmaf(v6.w, c6, fmaf(v7.w, c7, acc.w))));
    }
    for (; e + 4 <= dn; e += 4) {
        int s0 = row[e + 0], s1 = row[e + 1], s2 = row[e + 2], s3 = row[e + 3];
        float c0 = xs[s0], c1 = xs[s1], c2 = xs[s2], c3 = xs[s3];
        float4 v0 = i8x4_to_f4(X8[(size_t)s0 * 32 + lane]);
        float4 v1 = i8x4_to_f4(X8[(size_t)s1 * 32 + lane]);
        float4 v2 = i8x4_to_f4(X8[(size_t)s2 * 32 + lane]);
        float4 v3 = i8x4_to_f4(X8[(size_t)s3 * 32 + lane]);
        acc.x = fmaf(v0.x, c0, fmaf(v1.x, c1, fmaf(v2.x, c2, fmaf(v3.x, c3, acc.x))));
        acc.y = fmaf(v0.y, c0, fmaf(v1.y, c1, fmaf(v2.y, c2, fmaf(v3.y, c3, acc.y))));
        acc.z = fmaf(v0.z, c0, fmaf(v1.z, c1, fmaf(v2.z, c2, fmaf(v3.z, c3, acc.z))));
        acc.w = fmaf(v0.w, c0, fmaf(v1.w, c1, fmaf(v2.w, c2, fmaf(v3.w, c3, acc.w))));
    }
    for (; e < dn; ++e) {
        int s = row[e];
        float c = xs[s];
        float4 v = i8x4_to_f4(X8[(size_t)s * 32 + lane]);
        acc.x = fmaf(v.x, c, acc.x);
        acc.y = fmaf(v.y, c, acc.y);
        acc.z = fmaf(v.z, c, acc.z);
        acc.w = fmaf(v.w, c, acc.w);
    }
    ushort4 o;
    o.x = f2b(acc.x); o.y = f2b(acc.y); o.z = f2b(acc.z); o.w = f2b(acc.w);
    ((ushort4*)Out)[(size_t)node * 32 + lane] = o;
}

// ===========================================================================
// Fused 3-layer MLP via MFMA 16x16x32 bf16 (fp32 accumulate), W staged in LDS
// (round-2 lesson: global-B MFMA is latency-bound, keep LDS staging).
// Block = 256 thr = 4 waves; 64 rows; wave w owns 16 rows (row-parallel).
// LDS: Hb 17.4K + Ws 34.8K = 52.2K -> 3 blocks/CU.
// Epilogue writes ub as fp8-e4m3 (x64 pre-scale) -> 1-line gather-2 rows.
// A-frag: A[m=lane&15][k=quad*8+j]; B-frag from Ws[n][k];
// C/D: col=lane&15, row=quad*4+reg (verified layouts, m89/m120).
// ===========================================================================
#define MLP_ROWS 64
#define HBST     136

__global__ __launch_bounds__(256)
void mlp3_mfma(const unsigned short* __restrict__ Hg,
               const unsigned short* __restrict__ w1t, const float* __restrict__ b1,
               const unsigned short* __restrict__ w2t, const float* __restrict__ b2,
               const unsigned short* __restrict__ w3t, const float* __restrict__ dinv,
               unsigned char* __restrict__ ub_out, int N)
{
    __shared__ unsigned short Hb[MLP_ROWS][HBST];
    __shared__ unsigned short Ws[DIM][HBST];

    const int tid  = threadIdx.x;
    const int wave = tid >> 6;        // 0..3
    const int lane = tid & 63;
    const int row0 = blockIdx.x * MLP_ROWS;

    // ---- load H tile (coalesced uint4 = 8 bf16): 1024 x 16 B, 4/thread ----
#pragma unroll
    for (int l = 0; l < 4; ++l) {
        int f  = tid + l * 256;       // 0..1023
        int r  = f >> 4;              // 0..63
        int c8 = (f & 15) << 3;       // 0,8,...,120
        int gr = row0 + r;
        uint4 v = make_uint4(0u, 0u, 0u, 0u);
        if (gr < N) v = *(const uint4*)&Hg[(size_t)gr * DIM + c8];
        *(uint4*)&Hb[r][c8] = v;
    }

    const int m0 = wave * 16;
    const int qa = lane >> 4;         // quad 0..3
    const int la = lane & 15;

    for (int layer = 0; layer < 3; ++layer) {
        const unsigned short* __restrict__ Wt =
            (layer == 0) ? w1t : (layer == 1) ? w2t : w3t;

        // ---- stage Wt[128][128] -> Ws: 2048 uint4, 8/thread (L2-hot) ----
        __syncthreads();   // prior-layer Ws reads (and layer-0 H load) done
#pragma unroll
        for (int l = 0; l < 8; ++l) {
            int f  = tid + l * 256;   // 0..2047
            int r  = f >> 4;          // 0..127
            int c8 = (f & 15) << 3;
            *(uint4*)&Ws[r][c8] = *(const uint4*)&Wt[(size_t)r * DIM + c8];
        }
        __syncthreads();

        // A fragments for this wave's 16 rows, all K (4 chunks of 32)
        bfrag afr[4];
#pragma unroll
        for (int kc = 0; kc < 4; ++kc)
            afr[kc] = *(const bfrag*)&Hb[m0 + la][kc * 32 + qa * 8];

        if (layer < 2) {
            const float* bias = (layer == 0) ? b1 : b2;
#pragma unroll
            for (int nt = 0; nt < 8; ++nt) {
                const int n0 = nt * 16;
                ffrag acc = {0.f, 0.f, 0.f, 0.f};
#pragma unroll
                for (int kc = 0; kc < 4; ++kc) {
                    bfrag bfr = *(const bfrag*)&Ws[n0 + la][kc * 32 + qa * 8];
                    acc = __builtin_amdgcn_mfma_f32_16x16x32_bf16(afr[kc], bfr, acc, 0, 0, 0);
                }
                float bn = bias[n0 + la];
#pragma unroll
                for (int r = 0; r < 4; ++r) {
                    float v = fmaxf(acc[r] + bn, 0.f);
                    Hb[m0 + qa * 4 + r][n0 + la] = f2b(v);
                }
            }
            // wave-private rows: program order suffices before next layer
        } else {
            float dv[4];
#pragma unroll
            for (int r = 0; r < 4; ++r) {
                int gr = row0 + m0 + qa * 4 + r;
                dv[r] = (gr < N) ? dinv[gr] * UB_SCALE : 0.f;
            }
#pragma unroll
            for (int nt = 0; nt < 8; ++nt) {
                const int n0 = nt * 16;
                ffrag acc = {0.f, 0.f, 0.f, 0.f};
#pragma unroll
                for (int kc = 0; kc < 4; ++kc) {
                    bfrag bfr = *(const bfrag*)&Ws[n0 + la][kc * 32 + qa * 8];
                    acc = __builtin_amdgcn_mfma_f32_16x16x32_bf16(afr[kc], bfr, acc, 0, 0, 0);
                }
#pragma unroll
                for (int r = 0; r < 4; ++r) {
                    int gr = row0 + m0 + qa * 4 + r;
                    if (gr < N)
                        ub_out[(size_t)gr * DIM + n0 + la] = f_to_fp8(dv[r] * acc[r]);
                }
            }
        }
    }
}

// ===========================================================================
// Fused GCN gather (fp8 u, ELL) + finalize + global_add_pool (round-4 win).
// ub rows are 128 B fp8 (x64 pre-scaled): one cache line per random row.
// Decode via hw v_cvt_f32_fp8; 1/64 descale folds into di at finalize.
// P2_NODES=64: shorter runs double pool-atomic WRITE and regress; keep.
// ===========================================================================
#define P2_NODES 64
__global__ __launch_bounds__(256)
void gcn_gather_pool(const int* __restrict__ deg, const int* __restrict__ ell,
                     const unsigned char* __restrict__ ub,
                     const float* __restrict__ bias, const int* __restrict__ batch,
                     float* __restrict__ g, int N)
{
    const int grp  = threadIdx.x >> 5;
    const int lane = threadIdx.x & 31;
    const int n0   = blockIdx.x * P2_NODES + grp * 8;
    const unsigned* U4 = (const unsigned*)ub;   // 32 x uint per 128B row

    float4 bj;
    bj.x = bias[lane * 4 + 0];
    bj.y = bias[lane * 4 + 1];
    bj.z = bias[lane * 4 + 2];
    bj.w = bias[lane * 4 + 3];

    float4 lsum = make_float4(0.f, 0.f, 0.f, 0.f);
    int prev = -1;

    for (int k = 0; k < 8; ++k) {
        int node = n0 + k;
        if (node >= N) break;
        int dn = deg[node];
        const int* row = ell + node * ELLW;
        float4 acc = fp8x4_to_f4(U4[(size_t)node * 32 + lane]);  // self term
        int e = 0;
        for (; e + 8 <= dn; e += 8) {
            int s0 = row[e + 0], s1 = row[e + 1], s2 = row[e + 2], s3 = row[e + 3];
            int s4 = row[e + 4], s5 = row[e + 5], s6 = row[e + 6], s7 = row[e + 7];
            unsigned w0 = U4[(size_t)s0 * 32 + lane];
            unsigned w1 = U4[(size_t)s1 * 32 + lane];
            unsigned w2 = U4[(size_t)s2 * 32 + lane];
            unsigned w3 = U4[(size_t)s3 * 32 + lane];
            unsigned w4 = U4[(size_t)s4 * 32 + lane];
            unsigned w5 = U4[(size_t)s5 * 32 + lane];
            unsigned w6 = U4[(size_t)s6 * 32 + lane];
            unsigned w7 = U4[(size_t)s7 * 32 + lane];
            float4 v0 = fp8x4_to_f4(w0);
            float4 v1 = fp8x4_to_f4(w1);
            float4 v2 = fp8x4_to_f4(w2);
            float4 v3 = fp8x4_to_f4(w3);
            float4 v4 = fp8x4_to_f4(w4);
            float4 v5 = fp8x4_to_f4(w5);
            float4 v6 = fp8x4_to_f4(w6);
            float4 v7 = fp8x4_to_f4(w7);
            acc.x += (v0.x + v1.x + v2.x + v3.x) + (v4.x + v5.x + v6.x + v7.x);
            acc.y += (v0.y + v1.y + v2.y + v3.y) + (v4.y + v5.y + v6.y + v7.y);
            acc.z += (v0.z + v1.z + v2.z + v3.z) + (v4.z + v5.z + v6.z + v7.z);
            acc.w += (v0.w + v1.w + v2.w + v3.w) + (v4.w + v5.w + v6.w + v7.w);
        }
        for (; e + 4 <= dn; e += 4) {
            int s0 = row[e + 0], s1 = row[e + 1], s2 = row[e + 2], s3 = row[e + 3];
            float4 v0 = fp8x4_to_f4(U4[(size_t)s0 * 32 + lane]);
            float4 v1 = fp8x4_to_f4(U4[(size_t)s1 * 32 + lane]);
            float4 v2 = fp8x4_to_f4(U4[(size_t)s2 * 32 + lane]);
            float4 v3 = fp8x4_to_f4(U4[(size_t)s3 * 32 + lane]);
            acc.x += v0.x + v1.x + v2.x + v3.x;
            acc.y += v0.y + v1.y + v2.y + v3.y;
            acc.z += v0.z + v1.z + v2.z + v3.z;
            acc.w += v0.w + v1.w + v2.w + v3.w;
        }
        for (; e < dn; ++e) {
            int s = row[e];
            float4 v = fp8x4_to_f4(U4[(size_t)s * 32 + lane]);
            acc.x += v.x; acc.y += v.y; acc.z += v.z; acc.w += v.w;
        }
        // descale (1/64) folded into di
        float di = rsqrtf((float)dn + 1.0f) * UB_INVSCALE;
        float4 h;
        h.x = fmaxf(fmaf(di, acc.x, bj.x), 0.f);
        h.y = fmaxf(fmaf(di, acc.y, bj.y), 0.f);
        h.z = fmaxf(fmaf(di, acc.z, bj.z), 0.f);
        h.w = fmaxf(fmaf(di, acc.w, bj.w), 0.f);

        int b = batch[node];
        if (b != prev) {
            if (prev >= 0) {
                float* gp = &g[(size_t)prev * DIM + lane * 4];
                atomicAdd(gp + 0, lsum.x);
                atomicAdd(gp + 1, lsum.y);
                atomicAdd(gp + 2, lsum.z);
                atomicAdd(gp + 3, lsum.w);
            }
            lsum = make_float4(0.f, 0.f, 0.f, 0.f);
            prev = b;
        }
        lsum.x += h.x; lsum.y += h.y; lsum.z += h.z; lsum.w += h.w;
    }
    if (prev >= 0) {
        float* gp = &g[(size_t)prev * DIM + lane * 4];
        atomicAdd(gp + 0, lsum.x);
        atomicAdd(gp + 1, lsum.y);
        atomicAdd(gp + 2, lsum.z);
        atomicAdd(gp + 3, lsum.w);
    }
}

// ===========================================================================
// Head: out[gid] = relu(g[gid] @ lin1_w + b1) @ lin2_w + b2
// ===========================================================================
__global__ __launch_bounds__(128)
void head_kernel(const float* __restrict__ g, const float* __restrict__ w1,
                 const float* __restrict__ b1, const float* __restrict__ w2,
                 const float* __restrict__ b2, float* __restrict__ out)
{
    __shared__ float gs[DIM];
    __shared__ float red[6];
    int gid = blockIdx.x;
    int t = threadIdx.x;

    gs[t] = g[(size_t)gid * DIM + t];
    __syncthreads();

    float acc = b1[t];
#pragma unroll
    for (int k = 0; k < DIM; ++k) acc = fmaf(gs[k], w1[k * DIM + t], acc);
    float h = fmaxf(acc, 0.f);

    float c0 = h * w2[t * 3 + 0];
    float c1 = h * w2[t * 3 + 1];
    float c2 = h * w2[t * 3 + 2];
#pragma unroll
    for (int off = 32; off >= 1; off >>= 1) {
        c0 += __shfl_down(c0, off);
        c1 += __shfl_down(c1, off);
        c2 += __shfl_down(c2, off);
    }
    int wave = t >> 6;
    if ((t & 63) == 0) {
        red[wave * 3 + 0] = c0;
        red[wave * 3 + 1] = c1;
        red[wave * 3 + 2] = c2;
    }
    __syncthreads();
    if (t == 0) {
        out[(size_t)gid * 3 + 0] = red[0] + red[3] + b2[0];
        out[(size_t)gid * 3 + 1] = red[1] + red[4] + b2[1];
        out[(size_t)gid * 3 + 2] = red[2] + red[5] + b2[2];
    }
}

// ===========================================================================
extern "C" void kernel_launch(void* const* d_in, const int* in_sizes, int n_in,
                              void* d_out, int out_size, void* d_ws, size_t ws_size,
                              hipStream_t stream)
{
    const float* x       = (const float*)d_in[0];
    const int*   eidx    = (const int*)d_in[1];
    const int*   batch   = (const int*)d_in[2];
    const float* gin_w1  = (const float*)d_in[3];
    const float* gin_b1  = (const float*)d_in[4];
    const float* gin_w2  = (const float*)d_in[5];
    const float* gin_b2  = (const float*)d_in[6];
    const float* gcn_w   = (const float*)d_in[7];
    const float* gcn_b   = (const float*)d_in[8];
    const float* lin1_w  = (const float*)d_in[9];
    const float* lin1_b  = (const float*)d_in[10];
    const float* lin2_w  = (const float*)d_in[11];
    const float* lin2_b  = (const float*)d_in[12];

    const int* src = eidx;
    const int* dst = eidx + N_EDGES;

    // workspace carve (256B aligned)
    const size_t NBH = (size_t)N_NODES * DIM * sizeof(unsigned short); // 25.6 MB
    const size_t NB8 = (size_t)N_NODES * DIM;                          // 12.8 MB
    const size_t WTB = (size_t)DIM * DIM * sizeof(unsigned short);     // 32 KB
    char* base = (char*)d_ws;
    size_t off = 0;
    auto carve = [&](size_t bytes) {
        char* p = base + off;
        off = (off + bytes + 255) & ~(size_t)255;
        return p;
    };
    unsigned*       x8  = (unsigned*)      carve(NB8);  // x int8 (per-row scale)
    float*          xsc = (float*)         carve(N_NODES * sizeof(float));
    unsigned short* hb  = (unsigned short*)carve(NBH);  // gathered H in bf16
    unsigned char*  ub8 = (unsigned char*) carve(NB8);  // u in fp8 e4m3 (x64)
    unsigned short* w1t = (unsigned short*)carve(WTB);  // gin_w1^T bf16
    unsigned short* w2t = (unsigned short*)carve(WTB);
    unsigned short* w3t = (unsigned short*)carve(WTB);
    int*   cursor = (int*)  carve(N_NODES * sizeof(int));              // -> deg
    int*   ell    = (int*)  carve((size_t)N_NODES * ELLW * sizeof(int)); // 25.6MB
    float* dinv   = (float*)carve(N_NODES * sizeof(float));
    float* g      = (float*)carve((size_t)N_GRAPHS * DIM * sizeof(float));

    const int ngrid = (N_NODES + 7) / 8;
    const int mgrid = (N_NODES + MLP_ROWS - 1) / MLP_ROWS;
    const int pgrid = (N_NODES + P2_NODES - 1) / P2_NODES;

    // ---- zero cursor, then merged cast + quantize + ELL-fill ----
    hipMemsetAsync(cursor, 0, N_NODES * sizeof(int), stream);
    cast_fill<<<CF_FILL_BLOCKS + CF_ROW_BLOCKS + CF_WT_BLOCKS, 256, 0, stream>>>(
        x, x8, xsc, gin_w1, w1t, gin_w2, w2t, gcn_w, w3t,
        src, dst, cursor, ell, g, N_EDGES);

    // ---- GIN gather (int8 in, bf16 out, fp32 acc); also writes dinv ----
    ell_gather_i8<<<ngrid, 256, 0, stream>>>(cursor, ell, x8, xsc, hb, dinv,
                                             N_NODES);

    // ---- fused 3-layer MLP via MFMA (W staged in LDS) -> u (fp8) ----
    mlp3_mfma<<<mgrid, 256, 0, stream>>>(hb, w1t, gin_b1, w2t, gin_b2,
                                         w3t, dinv, ub8, N_NODES);

    // ---- fused GCN gather (fp8) + finalize + pool -> g ----
    gcn_gather_pool<<<pgrid, 256, 0, stream>>>(cursor, ell, ub8, gcn_b,
                                               batch, g, N_NODES);

    // ---- head ----
    head_kernel<<<N_GRAPHS, 128, 0, stream>>>(
        g, lin1_w, lin1_b, lin2_w, lin2_b, (float*)d_out);
}